// Round 2
// baseline (982.860 us; speedup 1.0000x reference)
//
#include <hip/hip_runtime.h>
#include <cstddef>

#define NB 16
#define NM 512
#define NHID 256
#define NHEAD 8
#define DHEAD 32
#define NTOPK 32
#define NROWS (NB*NM)
#define NLAYER 4

__device__ __forceinline__ float mish_f(float t) {
    float sp = (t > 20.0f) ? t : log1pf(__expf(t));
    return t * tanhf(sp);
}

// ---------------- top-k (once): bitonic sort 512 keys per row ----------------
// key = (INV(valbits) << 32) | idx  -> ascending key == descending value, ties by smaller idx
__global__ __launch_bounds__(512) void topk_kernel(const float* __restrict__ edge,
                                                   int* __restrict__ tidx,
                                                   float* __restrict__ tw) {
    __shared__ unsigned long long keys[NM];
    const int row = blockIdx.x;
    const int t = threadIdx.x;
    float v = edge[(size_t)row * NM + t];
    unsigned vb = __float_as_uint(v);  // uniform[0,1): non-negative -> bits monotone
    keys[t] = ((unsigned long long)(0xFFFFFFFFu - vb) << 32) | (unsigned)t;
    __syncthreads();
    for (int k = 2; k <= NM; k <<= 1) {
        for (int j = k >> 1; j > 0; j >>= 1) {
            int ixj = t ^ j;
            if (ixj > t) {
                unsigned long long a = keys[t], c = keys[ixj];
                bool up = ((t & k) == 0);
                if ((a > c) == up) { keys[t] = c; keys[ixj] = a; }
            }
            __syncthreads();
        }
    }
    if (t < NTOPK) {
        unsigned long long kk = keys[t];
        int idx = (int)(unsigned)(kk & 0xFFFFFFFFull);
        float val = __uint_as_float(0xFFFFFFFFu - (unsigned)(kk >> 32));
        float s = val;
        #pragma unroll
        for (int off = 16; off > 0; off >>= 1) s += __shfl_xor(s, off);
        tidx[row * NTOPK + t] = idx;
        tw[row * NTOPK + t] = val / (s + 1e-5f);
    }
}

// ---------------- LayerNorm (torch-style: unbiased var, eps on std) ----------
// one wave per row; safe in-place (each thread writes only elements it read)
__global__ __launch_bounds__(256) void ln_kernel(const float* __restrict__ x,
                                                 float* __restrict__ y,
                                                 const float* __restrict__ ga,
                                                 const float* __restrict__ gb) {
    const int wave = threadIdx.x >> 6;
    const int lane = threadIdx.x & 63;
    const int row = blockIdx.x * 4 + wave;
    const float* xr = x + (size_t)row * NHID;
    float v[4];
    float sum = 0.f;
    #pragma unroll
    for (int i = 0; i < 4; ++i) { v[i] = xr[lane + 64 * i]; sum += v[i]; }
    #pragma unroll
    for (int off = 32; off > 0; off >>= 1) sum += __shfl_xor(sum, off);
    float mean = sum * (1.0f / NHID);
    float var = 0.f;
    #pragma unroll
    for (int i = 0; i < 4; ++i) { float d = v[i] - mean; var += d * d; }
    #pragma unroll
    for (int off = 32; off > 0; off >>= 1) var += __shfl_xor(var, off);
    var *= (1.0f / (NHID - 1));
    float r = 1.0f / (sqrtf(var) + 1e-6f);
    float* yr = y + (size_t)row * NHID;
    #pragma unroll
    for (int i = 0; i < 4; ++i) {
        int c = lane + 64 * i;
        yr[c] = ga[c] * (v[i] - mean) * r + gb[c];
    }
}

// ---------------- GEMM: C[M,N] = A[M,256] * Bw[N,256]^T + bias, epilogue -----
// MODE 0: +bias; MODE 1: mish(+bias); MODE 2: res + mish(+bias)
template<int MODE>
__global__ __launch_bounds__(256) void gemm_nt(const float* __restrict__ A,
                                               const float* __restrict__ Bw,
                                               const float* __restrict__ bias,
                                               const float* __restrict__ res,
                                               float* __restrict__ C, int N) {
    __shared__ __align__(16) float As[32][68];
    __shared__ __align__(16) float Bs[32][68];
    const int bm = blockIdx.x * 64, bn = blockIdx.y * 64;
    const int tid = threadIdx.x;
    const int tx = tid & 15, ty = tid >> 4;
    const int lr = tid >> 3;          // 0..31
    const int lk = (tid & 7) << 2;    // 0,4,..,28
    float acc[4][4] = {};
    const float* Ar0 = A + (size_t)(bm + lr) * 256 + lk;
    const float* Ar1 = Ar0 + 32 * 256;
    const float* Br0 = Bw + (size_t)(bn + lr) * 256 + lk;
    const float* Br1 = Br0 + 32 * 256;
    for (int k0 = 0; k0 < 256; k0 += 32) {
        float4 a0 = *(const float4*)(Ar0 + k0);
        float4 a1 = *(const float4*)(Ar1 + k0);
        float4 b0 = *(const float4*)(Br0 + k0);
        float4 b1 = *(const float4*)(Br1 + k0);
        __syncthreads();
        As[lk+0][lr] = a0.x; As[lk+1][lr] = a0.y; As[lk+2][lr] = a0.z; As[lk+3][lr] = a0.w;
        As[lk+0][lr+32] = a1.x; As[lk+1][lr+32] = a1.y; As[lk+2][lr+32] = a1.z; As[lk+3][lr+32] = a1.w;
        Bs[lk+0][lr] = b0.x; Bs[lk+1][lr] = b0.y; Bs[lk+2][lr] = b0.z; Bs[lk+3][lr] = b0.w;
        Bs[lk+0][lr+32] = b1.x; Bs[lk+1][lr+32] = b1.y; Bs[lk+2][lr+32] = b1.z; Bs[lk+3][lr+32] = b1.w;
        __syncthreads();
        #pragma unroll
        for (int k = 0; k < 32; ++k) {
            float4 av = *(const float4*)&As[k][ty << 2];
            float4 bv = *(const float4*)&Bs[k][tx << 2];
            acc[0][0] += av.x * bv.x; acc[0][1] += av.x * bv.y; acc[0][2] += av.x * bv.z; acc[0][3] += av.x * bv.w;
            acc[1][0] += av.y * bv.x; acc[1][1] += av.y * bv.y; acc[1][2] += av.y * bv.z; acc[1][3] += av.y * bv.w;
            acc[2][0] += av.z * bv.x; acc[2][1] += av.z * bv.y; acc[2][2] += av.z * bv.z; acc[2][3] += av.z * bv.w;
            acc[3][0] += av.w * bv.x; acc[3][1] += av.w * bv.y; acc[3][2] += av.w * bv.z; acc[3][3] += av.w * bv.w;
        }
    }
    #pragma unroll
    for (int i = 0; i < 4; ++i) {
        int rrow = bm + (ty << 2) + i;
        #pragma unroll
        for (int j = 0; j < 4; ++j) {
            int col = bn + (tx << 2) + j;
            float v = acc[i][j] + bias[col];
            if (MODE >= 1) v = mish_f(v);
            size_t idx = (size_t)rrow * N + col;
            if (MODE == 2) v += res[idx];
            C[idx] = v;
        }
    }
}

// ---------------- V column-sum partials: part[b][s][c] = sum_{n in slice} v --
// KV layout: [8192][512], cols 0-255 = K, 256-511 = V
__global__ __launch_bounds__(256) void vpart_kernel(const float* __restrict__ kv,
                                                    float* __restrict__ part) {
    const int b = blockIdx.x, s = blockIdx.y;
    const int t = threadIdx.x;
    float acc = 0.f;
    const float* base = kv + ((size_t)(b * NM + s * 64)) * 512 + 256 + t;
    #pragma unroll 4
    for (int n = 0; n < 64; ++n) acc += base[(size_t)n * 512];
    part[((size_t)(b * 8 + s)) * NHID + t] = acc;
}

// ---------------- sparse attention -------------------------------------------
// out[m,c] = (sum_{j in topK}(e_j - 1) v_j[c] + Vsum[c]) / (sum(e_j - 1) + 512)
// IN-PLACE on qbuf: block `row` reads only qbuf[row], then overwrites qbuf[row].
__global__ __launch_bounds__(256) void attn_kernel(float* __restrict__ qbuf,
                                                   const float* __restrict__ kv,
                                                   const int* __restrict__ tidx,
                                                   const float* __restrict__ tw,
                                                   const int* __restrict__ masks,
                                                   const float* __restrict__ part) {
    const int row = blockIdx.x;
    const int b = row >> 9;
    const int t = threadIdx.x;   // t = head*32 + d
    __shared__ int sidx[NTOPK];
    __shared__ float sws[NTOPK];
    __shared__ int smask[NTOPK];
    if (t < NTOPK) {
        int idx = tidx[row * NTOPK + t];
        sidx[t] = idx;
        sws[t] = tw[row * NTOPK + t] * 0.17677669529663687f;  // *1/sqrt(32)
        smask[t] = (masks[b * NM + idx] == 0);
    }
    __syncthreads();
    float q = qbuf[(size_t)row * NHID + t];
    float vs = 0.f;
    #pragma unroll
    for (int s = 0; s < 8; ++s) vs += part[((size_t)(b * 8 + s)) * NHID + t];
    float acc = 0.f, den = 0.f;
    for (int j = 0; j < NTOPK; ++j) {
        size_t base = ((size_t)(b * NM + sidx[j])) * 512;
        float kk = kv[base + t];
        float vv = kv[base + 256 + t];
        float p = q * kk;
        p += __shfl_xor(p, 16); p += __shfl_xor(p, 8); p += __shfl_xor(p, 4);
        p += __shfl_xor(p, 2);  p += __shfl_xor(p, 1);
        float sarg = smask[j] ? -1e12f : p;        // mask applied BEFORE *ew*scale (as ref)
        float e = __expf(sarg * sws[j]);
        float em1 = e - 1.0f;
        acc += em1 * vv;
        den += em1;
    }
    qbuf[(size_t)row * NHID + t] = (acc + vs) / (den + 512.0f);
}

extern "C" void kernel_launch(void* const* d_in, const int* in_sizes, int n_in,
                              void* d_out, int out_size, void* d_ws, size_t ws_size,
                              hipStream_t stream) {
    (void)in_sizes; (void)n_in; (void)out_size; (void)ws_size;
    const float* node  = (const float*)d_in[0];
    const float* edge  = (const float*)d_in[1];
    const int*   msk   = (const int*)d_in[2];
    const float* attnW = (const float*)d_in[3];
    const float* attnB = (const float*)d_in[4];
    const float* ffnW  = (const float*)d_in[5];
    const float* ffnB  = (const float*)d_in[6];
    const float* lna   = (const float*)d_in[7];
    const float* lnb   = (const float*)d_in[8];

    float* x   = (float*)d_out;           // running activation [8192,256]
    float* wsf = (float*)d_ws;
    // compact workspace layout: 6,848,512 floats = 26.1 MB total
    float* q    = wsf;                    // 2,097,152 f  [8192,256] (Q / attn out / ffn hidden)
    float* kvb  = wsf + 2097152;          // 4,194,304 f  [8192,512] (K|V)
    float* tw   = wsf + 6291456;          //   262,144 f
    float* part = wsf + 6553600;          //    32,768 f  [16,8,256]
    int*   tidx = (int*)(wsf + 6586368);  //   262,144 i

    hipMemcpyAsync(x, node, (size_t)NROWS * NHID * sizeof(float),
                   hipMemcpyDeviceToDevice, stream);
    topk_kernel<<<NROWS, NM, 0, stream>>>(edge, tidx, tw);

    for (int l = 0; l < NLAYER; ++l) {
        const float* Wq = attnW + (size_t)l * 4 * NHID * NHID;
        const float* bq = attnB + (size_t)l * 4 * NHID;
        const float* Wkv = Wq + NHID * NHID;     // Wk,Wv contiguous
        const float* bkv = bq + NHID;
        const float* Wo  = Wq + 3 * NHID * NHID;
        const float* bo  = bq + 3 * NHID;
        // x <- LN(x)   (reference REPLACES x with its layernorm)
        ln_kernel<<<2048, 256, 0, stream>>>(x, x, lna, lnb);
        // q = x @ Wq^T + bq ; kv = x @ [Wk;Wv]^T + b
        gemm_nt<0><<<dim3(128, 4), 256, 0, stream>>>(x, Wq, bq, nullptr, q, 256);
        gemm_nt<0><<<dim3(128, 8), 256, 0, stream>>>(x, Wkv, bkv, nullptr, kvb, 512);
        // V column-sum partials
        vpart_kernel<<<dim3(16, 8), 256, 0, stream>>>(kvb, part);
        // sparse attention, in-place q -> attn_out
        attn_kernel<<<NROWS, 256, 0, stream>>>(q, kvb, tidx, tw, msk, part);
        // x = x + mish(q @ Wo^T + bo)
        gemm_nt<2><<<dim3(128, 4), 256, 0, stream>>>(q, Wo, bo, x, x, 256);
        // x <- LN(x)
        ln_kernel<<<2048, 256, 0, stream>>>(x, x, lna, lnb);
        // q = mish(x @ W1^T + b1)
        gemm_nt<1><<<dim3(128, 4), 256, 0, stream>>>(
            x, ffnW + (size_t)l * 2 * NHID * NHID, ffnB + (size_t)l * 2 * NHID,
            nullptr, q, 256);
        // x = x + mish(q @ W2^T + b2)
        gemm_nt<2><<<dim3(128, 4), 256, 0, stream>>>(
            q, ffnW + (size_t)(l * 2 + 1) * NHID * NHID, ffnB + (size_t)(l * 2 + 1) * NHID,
            x, x, 256);
    }
}

// Round 3
// 791.943 us; speedup vs baseline: 1.2411x; 1.2411x over previous
//
#include <hip/hip_runtime.h>
#include <cstddef>

#define NB 16
#define NM 512
#define NHID 256
#define NTOPK 32
#define NROWS (NB*NM)
#define NLAYER 4

typedef unsigned short ushort_t;
typedef __attribute__((ext_vector_type(8))) short short8;
typedef __attribute__((ext_vector_type(4))) float f32x4;

__device__ __forceinline__ float mish_f(float t) {
    float sp = (t > 20.0f) ? t : log1pf(__expf(t));
    return t * tanhf(sp);
}
__device__ __forceinline__ ushort_t f2b(float f) {   // fp32 -> bf16 RNE
    unsigned u = __float_as_uint(f);
    return (ushort_t)((u + 0x7FFFu + ((u >> 16) & 1u)) >> 16);
}
__device__ __forceinline__ float b2f(ushort_t h) {
    return __uint_as_float(((unsigned)h) << 16);
}

// ---------------- top-k: barrier-free, one wave per row ----------------------
// key = (valbits << 9) | (511 - idx): larger key = larger value, tie -> smaller idx
// (matches stable double-argsort rank semantics). 32 x wave-argmax in registers.
__global__ __launch_bounds__(256) void topk_kernel(const float* __restrict__ edge,
                                                   int* __restrict__ tidx,
                                                   float* __restrict__ tw) {
    const int wave = threadIdx.x >> 6, lane = threadIdx.x & 63;
    const int row = blockIdx.x * 4 + wave;
    const float* er = edge + (size_t)row * NM;
    unsigned long long key[8];
    #pragma unroll
    for (int s = 0; s < 8; ++s) {
        float v = er[s * 64 + lane];               // uniform[0,1): bits monotone
        int idx = s * 64 + lane;
        key[s] = ((unsigned long long)__float_as_uint(v) << 9) | (unsigned)(511 - idx);
    }
    float ssum = 0.f, rval = 0.f;
    int ridx = 0;
    for (int i = 0; i < 32; ++i) {
        unsigned long long m = key[0];
        #pragma unroll
        for (int s = 1; s < 8; ++s) m = key[s] > m ? key[s] : m;
        #pragma unroll
        for (int off = 32; off > 0; off >>= 1) {
            unsigned long long o = __shfl_xor(m, off);
            m = o > m ? o : m;
        }
        ssum += __uint_as_float((unsigned)(m >> 9));
        if (lane == i) { ridx = 511 - (int)(m & 511u); rval = __uint_as_float((unsigned)(m >> 9)); }
        #pragma unroll
        for (int s = 0; s < 8; ++s) if (key[s] == m) key[s] = 0;   // keys unique (idx field)
    }
    if (lane < NTOPK) {
        tidx[row * NTOPK + lane] = ridx;
        tw[row * NTOPK + lane] = rval / (ssum + 1e-5f);
    }
}

// ---------------- LayerNorm: fp32 in-place + bf16 copy out -------------------
__global__ __launch_bounds__(256) void ln_kernel(const float* __restrict__ x,
                                                 float* __restrict__ y,
                                                 ushort_t* __restrict__ yb,
                                                 const float* __restrict__ ga,
                                                 const float* __restrict__ gb) {
    const int wave = threadIdx.x >> 6, lane = threadIdx.x & 63;
    const int row = blockIdx.x * 4 + wave;
    const float* xr = x + (size_t)row * NHID;
    float v[4], sum = 0.f;
    #pragma unroll
    for (int i = 0; i < 4; ++i) { v[i] = xr[lane + 64 * i]; sum += v[i]; }
    #pragma unroll
    for (int off = 32; off > 0; off >>= 1) sum += __shfl_xor(sum, off);
    float mean = sum * (1.0f / NHID);
    float var = 0.f;
    #pragma unroll
    for (int i = 0; i < 4; ++i) { float d = v[i] - mean; var += d * d; }
    #pragma unroll
    for (int off = 32; off > 0; off >>= 1) var += __shfl_xor(var, off);
    var *= (1.0f / (NHID - 1));
    float r = 1.0f / (sqrtf(var) + 1e-6f);
    float* yr = y + (size_t)row * NHID;
    ushort_t* ybr = yb + (size_t)row * NHID;
    #pragma unroll
    for (int i = 0; i < 4; ++i) {
        int c = lane + 64 * i;
        float o = ga[c] * (v[i] - mean) * r + gb[c];
        yr[c] = o;
        ybr[c] = f2b(o);
    }
}

// ---------------- weight conversion into MFMA-fragment layout ----------------
// wb[frag][ks][lane][j] = W[frag_row + (lane&15)][ks*32 + (lane>>4)*8 + j]  (bf16)
// frags 0..255: attnW ([L][1024][256]); frags 256..383: ffnW ([L][512][256])
__global__ __launch_bounds__(256) void wconv_kernel(const float* __restrict__ attnW,
                                                    const float* __restrict__ ffnW,
                                                    ushort_t* __restrict__ wb) {
    int t = blockIdx.x * 256 + threadIdx.x;      // 196608 threads
    int frag = t >> 9, r = t & 511;
    int ks = r >> 6, l = r & 63;
    const float* src;
    if (frag < 256) src = attnW + ((size_t)(frag >> 6) * 1024 + (frag & 63) * 16 + (l & 15)) * 256;
    else { int fi = frag - 256; src = ffnW + ((size_t)(fi >> 5) * 512 + (fi & 31) * 16 + (l & 15)) * 256; }
    src += ks * 32 + (l >> 4) * 8;
    short8 o;
    #pragma unroll
    for (int j = 0; j < 8; ++j) o[j] = (short)f2b(src[j]);
    *(short8*)(wb + (size_t)t * 8) = o;
}

// ---------------- MFMA GEMM: C[M,N] = A_bf16[M,256] @ W^T + bias -------------
// BM=128, BN=64, 4 waves (2x2), wave-tile 64x32, K staged fully in LDS (swizzled).
template<int OUT_BF16, int MISH, int RES>
__global__ __launch_bounds__(256) void gemm_mfma(const ushort_t* __restrict__ A,
                                                 const ushort_t* __restrict__ Wb,
                                                 const float* __restrict__ bias,
                                                 const float* res,
                                                 float* C, ushort_t* Cb, int N) {
    __shared__ __align__(16) char smem[128 * 512];
    const int tid = threadIdx.x;
    const int lane = tid & 63, wave = tid >> 6;
    const int wr = wave >> 1, wc = wave & 1;
    const int bm = blockIdx.x * 128;
    // stage A tile (128 rows x 512B), XOR-swizzled 16B units
    {
        const int gc = tid & 31, r0 = tid >> 5;
        #pragma unroll
        for (int i = 0; i < 16; ++i) {
            int row = i * 8 + r0;
            f32x4 v = *(const f32x4*)(A + (size_t)(bm + row) * 256 + gc * 8);
            *(f32x4*)(smem + row * 512 + ((gc * 16) ^ ((row & 7) << 4))) = v;
        }
    }
    __syncthreads();
    f32x4 acc[4][2] = {};
    int abase[4], asw[4];
    #pragma unroll
    for (int mi = 0; mi < 4; ++mi) {
        int row = wr * 64 + mi * 16 + (lane & 15);
        abase[mi] = row * 512;
        asw[mi] = (row & 7) << 4;
    }
    const int f0 = blockIdx.y * 4 + wc * 2;
    const ushort_t* wp0 = Wb + ((size_t)(f0 * 8) * 64 + lane) * 8;
    const ushort_t* wp1 = wp0 + (size_t)8 * 64 * 8;
    const int aoff = (lane >> 4) * 16;
    #pragma unroll
    for (int ks = 0; ks < 8; ++ks) {
        short8 b0 = *(const short8*)(wp0 + ks * 512);
        short8 b1 = *(const short8*)(wp1 + ks * 512);
        short8 a[4];
        #pragma unroll
        for (int mi = 0; mi < 4; ++mi)
            a[mi] = *(const short8*)(smem + abase[mi] + ((ks * 64 + aoff) ^ asw[mi]));
        #pragma unroll
        for (int mi = 0; mi < 4; ++mi) {
            acc[mi][0] = __builtin_amdgcn_mfma_f32_16x16x32_bf16(a[mi], b0, acc[mi][0], 0, 0, 0);
            acc[mi][1] = __builtin_amdgcn_mfma_f32_16x16x32_bf16(a[mi], b1, acc[mi][1], 0, 0, 0);
        }
    }
    const int col0 = blockIdx.y * 64 + wc * 32 + (lane & 15);
    const int rbase = bm + wr * 64 + (lane >> 4) * 4;
    #pragma unroll
    for (int ni = 0; ni < 2; ++ni) {
        int col = col0 + ni * 16;
        float bv = bias[col];
        #pragma unroll
        for (int mi = 0; mi < 4; ++mi) {
            #pragma unroll
            for (int j = 0; j < 4; ++j) {
                int rrow = rbase + mi * 16 + j;
                float v = acc[mi][ni][j] + bv;
                if (MISH) v = mish_f(v);
                size_t idx = (size_t)rrow * N + col;
                if (RES) v += res[idx];
                if (OUT_BF16) Cb[idx] = f2b(v); else C[idx] = v;
            }
        }
    }
}

// ---------------- V column-sum partials (bf16 KV) ----------------------------
__global__ __launch_bounds__(256) void vpart_kernel(const ushort_t* __restrict__ kv,
                                                    float* __restrict__ part) {
    const int b = blockIdx.x, s = blockIdx.y, t = threadIdx.x;
    float acc = 0.f;
    const ushort_t* base = kv + ((size_t)(b * NM + s * 64)) * 512 + 256 + t;
    #pragma unroll 4
    for (int n = 0; n < 64; ++n) acc += b2f(base[(size_t)n * 512]);
    part[((size_t)(b * 8 + s)) * NHID + t] = acc;
}

// ---------------- sparse attention (bf16 KV, bf16 out) -----------------------
__global__ __launch_bounds__(256) void attn_kernel(const float* __restrict__ qbuf,
                                                   const ushort_t* __restrict__ kv,
                                                   const int* __restrict__ tidx,
                                                   const float* __restrict__ tw,
                                                   const int* __restrict__ masks,
                                                   const float* __restrict__ part,
                                                   ushort_t* __restrict__ outb) {
    const int row = blockIdx.x;
    const int b = row >> 9;
    const int t = threadIdx.x;
    __shared__ int sidx[NTOPK];
    __shared__ float sws[NTOPK];
    __shared__ int smask[NTOPK];
    if (t < NTOPK) {
        int idx = tidx[row * NTOPK + t];
        sidx[t] = idx;
        sws[t] = tw[row * NTOPK + t] * 0.17677669529663687f;  // * 1/sqrt(32)
        smask[t] = (masks[b * NM + idx] == 0);
    }
    __syncthreads();
    float q = qbuf[(size_t)row * NHID + t];
    float vs = 0.f;
    #pragma unroll
    for (int s = 0; s < 8; ++s) vs += part[((size_t)(b * 8 + s)) * NHID + t];
    float acc = 0.f, den = 0.f;
    for (int j = 0; j < NTOPK; ++j) {
        size_t base = ((size_t)(b * NM + sidx[j])) * 512;
        float kk = b2f(kv[base + t]);
        float vv = b2f(kv[base + 256 + t]);
        float p = q * kk;
        p += __shfl_xor(p, 16); p += __shfl_xor(p, 8); p += __shfl_xor(p, 4);
        p += __shfl_xor(p, 2);  p += __shfl_xor(p, 1);
        float sarg = smask[j] ? -1e12f : p;
        float e = __expf(sarg * sws[j]);
        float em1 = e - 1.0f;
        acc += em1 * vv;
        den += em1;
    }
    outb[(size_t)row * NHID + t] = f2b((acc + vs) / (den + 512.0f));
}

extern "C" void kernel_launch(void* const* d_in, const int* in_sizes, int n_in,
                              void* d_out, int out_size, void* d_ws, size_t ws_size,
                              hipStream_t stream) {
    (void)in_sizes; (void)n_in; (void)out_size; (void)ws_size;
    const float* node  = (const float*)d_in[0];
    const float* edge  = (const float*)d_in[1];
    const int*   msk   = (const int*)d_in[2];
    const float* attnW = (const float*)d_in[3];
    const float* attnB = (const float*)d_in[4];
    const float* ffnW  = (const float*)d_in[5];
    const float* ffnB  = (const float*)d_in[6];
    const float* lna   = (const float*)d_in[7];
    const float* lnb   = (const float*)d_in[8];

    float* x = (float*)d_out;                    // running activation [8192,256] fp32
    float* wsf = (float*)d_ws;
    // workspace (float-slot offsets), total 6,586,368 f = 25.1 MB (<= round-2's 26.1)
    float*    q    = wsf;                          // [8192,256] fp32 (Q; later hb alias)
    ushort_t* kvb  = (ushort_t*)(wsf + 2097152);   // [8192,512] bf16 (K|V)
    ushort_t* xb   = (ushort_t*)(wsf + 4194304);   // [8192,256] bf16 (LN out / attn out)
    ushort_t* wb   = (ushort_t*)(wsf + 5242880);   // 1,572,864 bf16 frag-layout weights
    float*    tw   = wsf + 6029312;                // [8192,32]
    float*    part = wsf + 6291456;                // [16,8,256]
    int*      tidx = (int*)(wsf + 6324224);        // [8192,32]
    ushort_t* hb   = (ushort_t*)q;                 // ffn hidden bf16 (aliases q region)

    hipMemcpyAsync(x, node, (size_t)NROWS * NHID * sizeof(float),
                   hipMemcpyDeviceToDevice, stream);
    wconv_kernel<<<768, 256, 0, stream>>>(attnW, ffnW, wb);
    topk_kernel<<<2048, 256, 0, stream>>>(edge, tidx, tw);

    for (int l = 0; l < NLAYER; ++l) {
        const ushort_t* Wq  = wb + (size_t)(l * 64) * 4096;
        const ushort_t* Wkv = wb + (size_t)(l * 64 + 16) * 4096;
        const ushort_t* Wo  = wb + (size_t)(l * 64 + 48) * 4096;
        const ushort_t* W1  = wb + (size_t)(256 + l * 32) * 4096;
        const ushort_t* W2  = wb + (size_t)(256 + l * 32 + 16) * 4096;
        const float* bq  = attnB + (size_t)l * 4 * NHID;
        const float* bkv = bq + NHID;
        const float* bo  = bq + 3 * NHID;
        const float* b1  = ffnB + (size_t)l * 2 * NHID;
        const float* b2  = b1 + NHID;

        // x <- LN(x) (fp32 in-place) + xb (bf16)
        ln_kernel<<<2048, 256, 0, stream>>>(x, x, xb, lna, lnb);
        // q = xb @ Wq^T + bq (fp32 out) ; kv = xb @ [Wk;Wv]^T + b (bf16 out)
        gemm_mfma<0,0,0><<<dim3(64, 4), 256, 0, stream>>>(xb, Wq, bq, nullptr, q, nullptr, 256);
        gemm_mfma<1,0,0><<<dim3(64, 8), 256, 0, stream>>>(xb, Wkv, bkv, nullptr, nullptr, kvb, 512);
        vpart_kernel<<<dim3(16, 8), 256, 0, stream>>>(kvb, part);
        // sparse attention -> xb (bf16; LN1 output already consumed)
        attn_kernel<<<NROWS, 256, 0, stream>>>(q, kvb, tidx, tw, msk, part, xb);
        // x = x + mish(xb @ Wo^T + bo)
        gemm_mfma<0,1,1><<<dim3(64, 4), 256, 0, stream>>>(xb, Wo, bo, x, x, nullptr, 256);
        // x <- LN(x) + xb
        ln_kernel<<<2048, 256, 0, stream>>>(x, x, xb, lna, lnb);
        // hb = mish(xb @ W1^T + b1) (bf16)
        gemm_mfma<1,1,0><<<dim3(64, 4), 256, 0, stream>>>(xb, W1, b1, nullptr, nullptr, hb, 256);
        // x = x + mish(hb @ W2^T + b2)
        gemm_mfma<0,1,1><<<dim3(64, 4), 256, 0, stream>>>(hb, W2, b2, x, x, nullptr, 256);
    }
}

// Round 4
// 365.929 us; speedup vs baseline: 2.6859x; 2.1642x over previous
//
#include <hip/hip_runtime.h>
#include <cstddef>

#define NB 16
#define NM 512
#define NHID 256
#define NTOPK 32
#define NROWS (NB*NM)
#define NLAYER 4

typedef unsigned short ushort_t;
typedef __attribute__((ext_vector_type(8))) short short8;
typedef __attribute__((ext_vector_type(4))) float f32x4;

__device__ __forceinline__ float mish_f(float t) {
    float sp = (t > 20.0f) ? t : log1pf(__expf(t));
    return t * tanhf(sp);
}
__device__ __forceinline__ ushort_t f2b(float f) {   // fp32 -> bf16 RNE
    unsigned u = __float_as_uint(f);
    return (ushort_t)((u + 0x7FFFu + ((u >> 16) & 1u)) >> 16);
}
__device__ __forceinline__ float b2f(ushort_t h) {
    return __uint_as_float(((unsigned)h) << 16);
}

// ---------------- top-k: ballot bisection, one wave per row ------------------
// Exact 32nd-largest via bitwise threshold build; exact index-order tie-break.
__global__ __launch_bounds__(256) void topk_kernel(const float* __restrict__ edge,
                                                   int* __restrict__ tidx,
                                                   float* __restrict__ tw) {
    const int lane = threadIdx.x & 63, w = threadIdx.x >> 6;
    const int row = blockIdx.x * 4 + w;
    const float* er = edge + (size_t)row * NM;
    float v[8]; unsigned u[8];
    #pragma unroll
    for (int s = 0; s < 8; ++s) { v[s] = er[s * 64 + lane]; u[s] = __float_as_uint(v[s]); }
    // build T = bits of the 32nd-largest value (values are non-negative floats)
    unsigned T = 0;
    for (int bit = 31; bit >= 0; --bit) {
        unsigned Tc = T | (1u << bit);
        int c = 0;
        #pragma unroll
        for (int s = 0; s < 8; ++s) c += (int)__popcll(__ballot(u[s] >= Tc));
        if (c >= NTOPK) T = Tc;
    }
    int cgt = 0;
    #pragma unroll
    for (int s = 0; s < 8; ++s) cgt += (int)__popcll(__ballot(u[s] > T));
    const int extra = NTOPK - cgt;           // number of ==T entries to keep (smallest idx first)
    // sum of selected values
    float psum = 0.f;
    #pragma unroll
    for (int s = 0; s < 8; ++s) psum += (u[s] > T) ? v[s] : 0.f;
    psum += __shfl_xor(psum, 1); psum += __shfl_xor(psum, 2); psum += __shfl_xor(psum, 4);
    psum += __shfl_xor(psum, 8); psum += __shfl_xor(psum, 16); psum += __shfl_xor(psum, 32);
    const float ssum = psum + (float)extra * __uint_as_float(T);
    const float den = ssum + 1e-5f;
    const unsigned long long lmask = (1ull << lane) - 1ull;
    int base = 0, eqbase = 0;
    #pragma unroll
    for (int s = 0; s < 8; ++s) {
        bool gt = (u[s] > T), eq = (u[s] == T);
        unsigned long long meq = __ballot(eq);
        int eqrank = eqbase + (int)__popcll(meq & lmask);
        bool sel = gt || (eq && eqrank < extra);
        unsigned long long msel = __ballot(sel);
        if (sel) {
            int pos = base + (int)__popcll(msel & lmask);
            tidx[row * NTOPK + pos] = s * 64 + lane;
            tw[row * NTOPK + pos] = v[s] / den;
        }
        base += (int)__popcll(msel);
        eqbase += (int)__popcll(meq);
    }
}

// ---------------- weight conversion into MFMA-fragment layout ----------------
// wb[frag][ks][lane][j] = W[frag*16 + (lane&15)][ks*32 + (lane>>4)*8 + j]  (bf16)
__global__ __launch_bounds__(256) void wconv_kernel(const float* __restrict__ attnW,
                                                    const float* __restrict__ ffnW,
                                                    ushort_t* __restrict__ wb) {
    int t = blockIdx.x * 256 + threadIdx.x;      // 196608 threads
    int frag = t >> 9, r = t & 511;
    int ks = r >> 6, l = r & 63;
    const float* src;
    if (frag < 256) src = attnW + ((size_t)(frag >> 6) * 1024 + (frag & 63) * 16 + (l & 15)) * 256;
    else { int fi = frag - 256; src = ffnW + ((size_t)(fi >> 5) * 512 + (fi & 31) * 16 + (l & 15)) * 256; }
    src += ks * 32 + (l >> 4) * 8;
    short8 o;
    #pragma unroll
    for (int j = 0; j < 8; ++j) o[j] = (short)f2b(src[j]);
    *(short8*)(wb + (size_t)t * 8) = o;
}

// ---------------- K1: LN1 + fused QKV GEMM (per 16-row block) ----------------
__global__ __launch_bounds__(256) void k1_ln_qkv(float* __restrict__ x,
                                                 float* __restrict__ q,
                                                 ushort_t* __restrict__ kvb,
                                                 const ushort_t* __restrict__ wf,
                                                 const float* __restrict__ bias,
                                                 const float* __restrict__ ga,
                                                 const float* __restrict__ gb) {
    __shared__ __align__(16) char af[8192];      // A-fragments, 16 rows x 256 cols bf16
    const int tid = threadIdx.x, lane = tid & 63, w = tid >> 6;
    const int bm = blockIdx.x * 16;
    // ---- LN: wave w -> rows w*4..+3; lane: rr=lane>>4, cols (lane&15)*16..+16
    {
        const int rr = lane >> 4, c16 = (lane & 15) << 4;
        const int ri = (w << 2) + rr;
        float* xr = x + (size_t)(bm + ri) * NHID + c16;
        f32x4 v0 = *(const f32x4*)(xr);
        f32x4 v1 = *(const f32x4*)(xr + 4);
        f32x4 v2 = *(const f32x4*)(xr + 8);
        f32x4 v3 = *(const f32x4*)(xr + 12);
        float s = 0.f;
        #pragma unroll
        for (int k = 0; k < 4; ++k) s += v0[k] + v1[k] + v2[k] + v3[k];
        s += __shfl_xor(s, 1); s += __shfl_xor(s, 2); s += __shfl_xor(s, 4); s += __shfl_xor(s, 8);
        float mean = s * (1.0f / NHID);
        float vr = 0.f;
        #pragma unroll
        for (int k = 0; k < 4; ++k) {
            float d0 = v0[k]-mean, d1 = v1[k]-mean, d2 = v2[k]-mean, d3 = v3[k]-mean;
            vr += d0*d0 + d1*d1 + d2*d2 + d3*d3;
        }
        vr += __shfl_xor(vr, 1); vr += __shfl_xor(vr, 2); vr += __shfl_xor(vr, 4); vr += __shfl_xor(vr, 8);
        vr *= (1.0f / (NHID - 1));
        float rs = 1.0f / (sqrtf(vr) + 1e-6f);
        f32x4 g0 = *(const f32x4*)(ga + c16), g1 = *(const f32x4*)(ga + c16 + 4);
        f32x4 g2 = *(const f32x4*)(ga + c16 + 8), g3 = *(const f32x4*)(ga + c16 + 12);
        f32x4 h0 = *(const f32x4*)(gb + c16), h1 = *(const f32x4*)(gb + c16 + 4);
        f32x4 h2 = *(const f32x4*)(gb + c16 + 8), h3 = *(const f32x4*)(gb + c16 + 12);
        f32x4 o0, o1, o2, o3;
        #pragma unroll
        for (int k = 0; k < 4; ++k) {
            o0[k] = g0[k]*(v0[k]-mean)*rs + h0[k];
            o1[k] = g1[k]*(v1[k]-mean)*rs + h1[k];
            o2[k] = g2[k]*(v2[k]-mean)*rs + h2[k];
            o3[k] = g3[k]*(v3[k]-mean)*rs + h3[k];
        }
        *(f32x4*)(xr) = o0; *(f32x4*)(xr + 4) = o1;
        *(f32x4*)(xr + 8) = o2; *(f32x4*)(xr + 12) = o3;
        short8 p0, p1;
        #pragma unroll
        for (int k = 0; k < 4; ++k) {
            p0[k] = (short)f2b(o0[k]); p0[4+k] = (short)f2b(o1[k]);
            p1[k] = (short)f2b(o2[k]); p1[4+k] = (short)f2b(o3[k]);
        }
        int c8 = (lane & 15) * 2;
        *(short8*)(af + (c8 >> 2) * 1024 + (ri + ((c8 & 3) << 4)) * 16) = p0;
        int c8b = c8 + 1;
        *(short8*)(af + (c8b >> 2) * 1024 + (ri + ((c8b & 3) << 4)) * 16) = p1;
    }
    __syncthreads();
    // ---- fused QKV GEMM: N=768, wave covers cols g*128 + w*32
    short8 a[8];
    #pragma unroll
    for (int ks = 0; ks < 8; ++ks) a[ks] = *(const short8*)(af + ks * 1024 + lane * 16);
    #pragma unroll
    for (int g = 0; g < 6; ++g) {
        const int col0 = g * 128 + w * 32;
        f32x4 acc0 = {}, acc1 = {};
        const ushort_t* bp0 = wf + ((size_t)((col0 >> 4) * 8) * 64 + lane) * 8;
        const ushort_t* bp1 = bp0 + 4096;
        #pragma unroll
        for (int ks = 0; ks < 8; ++ks) {
            short8 b0 = *(const short8*)(bp0 + ks * 512);
            short8 b1 = *(const short8*)(bp1 + ks * 512);
            acc0 = __builtin_amdgcn_mfma_f32_16x16x32_bf16(a[ks], b0, acc0, 0, 0, 0);
            acc1 = __builtin_amdgcn_mfma_f32_16x16x32_bf16(a[ks], b1, acc1, 0, 0, 0);
        }
        const int rbase = bm + (lane >> 4) * 4;
        #pragma unroll
        for (int ni = 0; ni < 2; ++ni) {
            int col = col0 + ni * 16 + (lane & 15);
            float bv = bias[col];
            f32x4 A = ni ? acc1 : acc0;
            #pragma unroll
            for (int j = 0; j < 4; ++j) {
                int row = rbase + j;
                float vv = A[j] + bv;
                if (col < 256) q[(size_t)row * 256 + col] = vv;
                else kvb[(size_t)row * 512 + (col - 256)] = f2b(vv);
            }
        }
    }
}

// ---------------- K2: vsum + attn + Wo + LN2 + FFN1 + FFN2 (per 32 rows) -----
__global__ __launch_bounds__(512) void k2_attn_ffn(float* __restrict__ x,
                                                   const float* __restrict__ q,
                                                   const ushort_t* __restrict__ kvb,
                                                   const int* __restrict__ tidx,
                                                   const float* __restrict__ tw,
                                                   const int* __restrict__ msk,
                                                   const ushort_t* __restrict__ wfo,
                                                   const ushort_t* __restrict__ wf1,
                                                   const ushort_t* __restrict__ wf2,
                                                   const float* __restrict__ bo,
                                                   const float* __restrict__ b1,
                                                   const float* __restrict__ b2,
                                                   const float* __restrict__ ga,
                                                   const float* __restrict__ gb) {
    __shared__ __align__(16) float regA[8192];   // 32KB: ph0 vsum partials; ph3+ x2/xc tile
    __shared__ __align__(16) char regB[16384];   // A-frag (attn-out, then xc)
    __shared__ __align__(16) char regC[16384];   // sidx/sws/vsumf, then h-frag
    const int tid = threadIdx.x, lane = tid & 63, w = tid >> 6;
    const int R0 = blockIdx.x * 32, bb = R0 >> 9;
    int* sidx = (int*)regC;
    float* sws = (float*)(regC + 4096);
    float* vsumf = (float*)(regC + 8192);
    // ---- ph0a: V column-sum partials (wave w sums 64 rows of batch bb)
    {
        const ushort_t* vb = kvb + ((size_t)(bb * NM + w * 64)) * 512 + 256 + lane * 4;
        float s0 = 0.f, s1 = 0.f, s2 = 0.f, s3 = 0.f;
        #pragma unroll 8
        for (int r = 0; r < 64; ++r) {
            const ushort_t* p = vb + (size_t)r * 512;
            s0 += b2f(p[0]); s1 += b2f(p[1]); s2 += b2f(p[2]); s3 += b2f(p[3]);
        }
        regA[w * 256 + lane * 4 + 0] = s0; regA[w * 256 + lane * 4 + 1] = s1;
        regA[w * 256 + lane * 4 + 2] = s2; regA[w * 256 + lane * 4 + 3] = s3;
    }
    // ---- ph1: topk lists for 32 rows (mask folded into sign bit)
    for (int i = tid; i < 1024; i += 512) {
        int r = i >> 5;
        int nb = tidx[(size_t)(R0 + r) * NTOPK + (i & 31)];
        float wv = tw[(size_t)(R0 + r) * NTOPK + (i & 31)] * 0.17677669529663687f;
        sidx[i] = (msk[bb * NM + nb] == 0) ? (nb | (int)0x80000000) : nb;
        sws[i] = wv;
    }
    __syncthreads();
    // ---- ph0b: reduce vsum partials
    if (tid < 256) {
        float s = 0.f;
        #pragma unroll
        for (int w8 = 0; w8 < 8; ++w8) s += regA[w8 * 256 + tid];
        vsumf[tid] = s;
    }
    __syncthreads();
    // ---- ph2: sparse attention; lane = (row rr, head h, half)
    {
        const int rr = lane >> 4;
        const int rl = (w << 2) + rr;            // local row 0..31
        const int row = R0 + rl;
        const int cbase = ((lane >> 1) & 7) * 32 + (lane & 1) * 16;
        const float* qp = q + (size_t)row * NHID + cbase;
        float qv[16];
        {
            f32x4 q0 = *(const f32x4*)(qp), q1 = *(const f32x4*)(qp + 4);
            f32x4 q2 = *(const f32x4*)(qp + 8), q3 = *(const f32x4*)(qp + 12);
            #pragma unroll
            for (int k = 0; k < 4; ++k) { qv[k]=q0[k]; qv[4+k]=q1[k]; qv[8+k]=q2[k]; qv[12+k]=q3[k]; }
        }
        float accv[16];
        #pragma unroll
        for (int k = 0; k < 16; ++k) accv[k] = 0.f;
        float den = 0.f;
        for (int j = 0; j < NTOPK; ++j) {
            int raw = sidx[rl * 32 + j];
            float swv = sws[rl * 32 + j];
            int nb = raw & 511;
            const ushort_t* kp = kvb + ((size_t)(bb * NM + nb)) * 512 + cbase;
            short8 kA = *(const short8*)(kp);
            short8 kB = *(const short8*)(kp + 8);
            short8 vA = *(const short8*)(kp + 256);
            short8 vB = *(const short8*)(kp + 264);
            float p = 0.f;
            #pragma unroll
            for (int t = 0; t < 8; ++t) p += qv[t] * b2f((ushort_t)kA[t]);
            #pragma unroll
            for (int t = 0; t < 8; ++t) p += qv[8 + t] * b2f((ushort_t)kB[t]);
            p += __shfl_xor(p, 1);
            float sarg = (raw < 0) ? -1e12f : p;
            float e = __expf(sarg * swv);
            float em1 = e - 1.0f;
            den += em1;
            #pragma unroll
            for (int t = 0; t < 8; ++t) accv[t] += em1 * b2f((ushort_t)vA[t]);
            #pragma unroll
            for (int t = 0; t < 8; ++t) accv[8 + t] += em1 * b2f((ushort_t)vB[t]);
        }
        float rden = 1.0f / (den + 512.0f);
        short8 p0, p1;
        #pragma unroll
        for (int t = 0; t < 8; ++t) {
            p0[t] = (short)f2b((accv[t] + vsumf[cbase + t]) * rden);
            p1[t] = (short)f2b((accv[8 + t] + vsumf[cbase + 8 + t]) * rden);
        }
        const int rb = rl >> 4, rif = rl & 15;
        int c8 = cbase >> 3;
        *(short8*)(regB + rb * 8192 + (c8 >> 2) * 1024 + (rif + ((c8 & 3) << 4)) * 16) = p0;
        int c8b = c8 + 1;
        *(short8*)(regB + rb * 8192 + (c8b >> 2) * 1024 + (rif + ((c8b & 3) << 4)) * 16) = p1;
    }
    __syncthreads();
    // ---- ph3: Wo GEMM + mish + residual(x_a) -> regA (x2 tile)
    {
        const int col0 = w * 32;
        f32x4 acc[2][2] = {};
        const ushort_t* bp0 = wfo + ((size_t)((col0 >> 4) * 8) * 64 + lane) * 8;
        const ushort_t* bp1 = bp0 + 4096;
        #pragma unroll
        for (int ks = 0; ks < 8; ++ks) {
            short8 a0 = *(const short8*)(regB + ks * 1024 + lane * 16);
            short8 a1 = *(const short8*)(regB + 8192 + ks * 1024 + lane * 16);
            short8 b0 = *(const short8*)(bp0 + ks * 512);
            short8 b1 = *(const short8*)(bp1 + ks * 512);
            acc[0][0] = __builtin_amdgcn_mfma_f32_16x16x32_bf16(a0, b0, acc[0][0], 0, 0, 0);
            acc[0][1] = __builtin_amdgcn_mfma_f32_16x16x32_bf16(a0, b1, acc[0][1], 0, 0, 0);
            acc[1][0] = __builtin_amdgcn_mfma_f32_16x16x32_bf16(a1, b0, acc[1][0], 0, 0, 0);
            acc[1][1] = __builtin_amdgcn_mfma_f32_16x16x32_bf16(a1, b1, acc[1][1], 0, 0, 0);
        }
        #pragma unroll
        for (int mi = 0; mi < 2; ++mi) {
            #pragma unroll
            for (int ni = 0; ni < 2; ++ni) {
                int col = col0 + ni * 16 + (lane & 15);
                float bv = bo[col];
                #pragma unroll
                for (int j = 0; j < 4; ++j) {
                    int row = mi * 16 + (lane >> 4) * 4 + j;
                    float v = mish_f(acc[mi][ni][j] + bv) + x[(size_t)(R0 + row) * NHID + col];
                    regA[row * 256 + col] = v;
                }
            }
        }
    }
    __syncthreads();
    // ---- ph4: LN2 on regA (in place) + frag -> regB
    {
        const int rr = lane >> 4, c16 = (lane & 15) << 4;
        const int rl = (w << 2) + rr;
        float* xr = regA + rl * 256 + c16;
        f32x4 v0 = *(const f32x4*)(xr);
        f32x4 v1 = *(const f32x4*)(xr + 4);
        f32x4 v2 = *(const f32x4*)(xr + 8);
        f32x4 v3 = *(const f32x4*)(xr + 12);
        float s = 0.f;
        #pragma unroll
        for (int k = 0; k < 4; ++k) s += v0[k] + v1[k] + v2[k] + v3[k];
        s += __shfl_xor(s, 1); s += __shfl_xor(s, 2); s += __shfl_xor(s, 4); s += __shfl_xor(s, 8);
        float mean = s * (1.0f / NHID);
        float vr = 0.f;
        #pragma unroll
        for (int k = 0; k < 4; ++k) {
            float d0 = v0[k]-mean, d1 = v1[k]-mean, d2 = v2[k]-mean, d3 = v3[k]-mean;
            vr += d0*d0 + d1*d1 + d2*d2 + d3*d3;
        }
        vr += __shfl_xor(vr, 1); vr += __shfl_xor(vr, 2); vr += __shfl_xor(vr, 4); vr += __shfl_xor(vr, 8);
        vr *= (1.0f / (NHID - 1));
        float rs = 1.0f / (sqrtf(vr) + 1e-6f);
        f32x4 g0 = *(const f32x4*)(ga + c16), g1 = *(const f32x4*)(ga + c16 + 4);
        f32x4 g2 = *(const f32x4*)(ga + c16 + 8), g3 = *(const f32x4*)(ga + c16 + 12);
        f32x4 h0 = *(const f32x4*)(gb + c16), h1 = *(const f32x4*)(gb + c16 + 4);
        f32x4 h2 = *(const f32x4*)(gb + c16 + 8), h3 = *(const f32x4*)(gb + c16 + 12);
        f32x4 o0, o1, o2, o3;
        #pragma unroll
        for (int k = 0; k < 4; ++k) {
            o0[k] = g0[k]*(v0[k]-mean)*rs + h0[k];
            o1[k] = g1[k]*(v1[k]-mean)*rs + h1[k];
            o2[k] = g2[k]*(v2[k]-mean)*rs + h2[k];
            o3[k] = g3[k]*(v3[k]-mean)*rs + h3[k];
        }
        *(f32x4*)(xr) = o0; *(f32x4*)(xr + 4) = o1;
        *(f32x4*)(xr + 8) = o2; *(f32x4*)(xr + 12) = o3;
        short8 p0, p1;
        #pragma unroll
        for (int k = 0; k < 4; ++k) {
            p0[k] = (short)f2b(o0[k]); p0[4+k] = (short)f2b(o1[k]);
            p1[k] = (short)f2b(o2[k]); p1[4+k] = (short)f2b(o3[k]);
        }
        const int rb = rl >> 4, rif = rl & 15;
        int c8 = (lane & 15) * 2;
        *(short8*)(regB + rb * 8192 + (c8 >> 2) * 1024 + (rif + ((c8 & 3) << 4)) * 16) = p0;
        int c8b = c8 + 1;
        *(short8*)(regB + rb * 8192 + (c8b >> 2) * 1024 + (rif + ((c8b & 3) << 4)) * 16) = p1;
    }
    __syncthreads();
    // ---- ph5: FFN1 (mish) -> h-frag in regC
    {
        const int col0 = w * 32;
        f32x4 acc[2][2] = {};
        const ushort_t* bp0 = wf1 + ((size_t)((col0 >> 4) * 8) * 64 + lane) * 8;
        const ushort_t* bp1 = bp0 + 4096;
        #pragma unroll
        for (int ks = 0; ks < 8; ++ks) {
            short8 a0 = *(const short8*)(regB + ks * 1024 + lane * 16);
            short8 a1 = *(const short8*)(regB + 8192 + ks * 1024 + lane * 16);
            short8 b0 = *(const short8*)(bp0 + ks * 512);
            short8 b1 = *(const short8*)(bp1 + ks * 512);
            acc[0][0] = __builtin_amdgcn_mfma_f32_16x16x32_bf16(a0, b0, acc[0][0], 0, 0, 0);
            acc[0][1] = __builtin_amdgcn_mfma_f32_16x16x32_bf16(a0, b1, acc[0][1], 0, 0, 0);
            acc[1][0] = __builtin_amdgcn_mfma_f32_16x16x32_bf16(a1, b0, acc[1][0], 0, 0, 0);
            acc[1][1] = __builtin_amdgcn_mfma_f32_16x16x32_bf16(a1, b1, acc[1][1], 0, 0, 0);
        }
        __syncthreads();   // regC topk/vsum data dead; safe to overwrite
        #pragma unroll
        for (int mi = 0; mi < 2; ++mi) {
            #pragma unroll
            for (int ni = 0; ni < 2; ++ni) {
                int col = col0 + ni * 16 + (lane & 15);
                float bv = b1[col];
                int c8 = col >> 3;
                #pragma unroll
                for (int j = 0; j < 4; ++j) {
                    int row = mi * 16 + (lane >> 4) * 4 + j;
                    float v = mish_f(acc[mi][ni][j] + bv);
                    *(ushort_t*)(regC + (row >> 4) * 8192 + (c8 >> 2) * 1024 +
                                 ((row & 15) + ((c8 & 3) << 4)) * 16 + (col & 7) * 2) = f2b(v);
                }
            }
        }
    }
    __syncthreads();
    // ---- ph6: FFN2 (mish) + residual(xc) -> global x
    {
        const int col0 = w * 32;
        f32x4 acc[2][2] = {};
        const ushort_t* bp0 = wf2 + ((size_t)((col0 >> 4) * 8) * 64 + lane) * 8;
        const ushort_t* bp1 = bp0 + 4096;
        #pragma unroll
        for (int ks = 0; ks < 8; ++ks) {
            short8 a0 = *(const short8*)(regC + ks * 1024 + lane * 16);
            short8 a1 = *(const short8*)(regC + 8192 + ks * 1024 + lane * 16);
            short8 b0 = *(const short8*)(bp0 + ks * 512);
            short8 b1 = *(const short8*)(bp1 + ks * 512);
            acc[0][0] = __builtin_amdgcn_mfma_f32_16x16x32_bf16(a0, b0, acc[0][0], 0, 0, 0);
            acc[0][1] = __builtin_amdgcn_mfma_f32_16x16x32_bf16(a0, b1, acc[0][1], 0, 0, 0);
            acc[1][0] = __builtin_amdgcn_mfma_f32_16x16x32_bf16(a1, b0, acc[1][0], 0, 0, 0);
            acc[1][1] = __builtin_amdgcn_mfma_f32_16x16x32_bf16(a1, b1, acc[1][1], 0, 0, 0);
        }
        #pragma unroll
        for (int mi = 0; mi < 2; ++mi) {
            #pragma unroll
            for (int ni = 0; ni < 2; ++ni) {
                int col = col0 + ni * 16 + (lane & 15);
                float bv = b2[col];
                #pragma unroll
                for (int j = 0; j < 4; ++j) {
                    int row = mi * 16 + (lane >> 4) * 4 + j;
                    float v = mish_f(acc[mi][ni][j] + bv) + regA[row * 256 + col];
                    x[(size_t)(R0 + row) * NHID + col] = v;
                }
            }
        }
    }
}

extern "C" void kernel_launch(void* const* d_in, const int* in_sizes, int n_in,
                              void* d_out, int out_size, void* d_ws, size_t ws_size,
                              hipStream_t stream) {
    (void)in_sizes; (void)n_in; (void)out_size; (void)ws_size;
    const float* node  = (const float*)d_in[0];
    const float* edge  = (const float*)d_in[1];
    const int*   msk   = (const int*)d_in[2];
    const float* attnW = (const float*)d_in[3];
    const float* attnB = (const float*)d_in[4];
    const float* ffnW  = (const float*)d_in[5];
    const float* ffnB  = (const float*)d_in[6];
    const float* lna   = (const float*)d_in[7];
    const float* lnb   = (const float*)d_in[8];

    float* x = (float*)d_out;                       // running activation [8192,256] fp32
    float* wsf = (float*)d_ws;
    // workspace: 5,505,024 floats = 21 MB
    float*    q    = wsf;                           // [8192,256] fp32
    ushort_t* kvb  = (ushort_t*)(wsf + 2097152);    // [8192,512] bf16
    ushort_t* wb   = (ushort_t*)(wsf + 4194304);    // 1,572,864 bf16 frag weights
    float*    tw   = wsf + 4980736;                 // [8192,32]
    int*      tidx = (int*)(wsf + 5242880);         // [8192,32]

    hipMemcpyAsync(x, node, (size_t)NROWS * NHID * sizeof(float),
                   hipMemcpyDeviceToDevice, stream);
    wconv_kernel<<<768, 256, 0, stream>>>(attnW, ffnW, wb);
    topk_kernel<<<2048, 256, 0, stream>>>(edge, tidx, tw);

    for (int l = 0; l < NLAYER; ++l) {
        k1_ln_qkv<<<512, 256, 0, stream>>>(
            x, q, kvb, wb + (size_t)(l * 64) * 4096, attnB + (size_t)l * 1024, lna, lnb);
        k2_attn_ffn<<<256, 512, 0, stream>>>(
            x, q, kvb, tidx, tw, msk,
            wb + (size_t)(l * 64 + 48) * 4096,
            wb + (size_t)(256 + l * 32) * 4096,
            wb + (size_t)(256 + l * 32 + 16) * 4096,
            attnB + (size_t)l * 1024 + 768,
            ffnB + (size_t)l * 512,
            ffnB + (size_t)l * 512 + 256,
            lna, lnb);
    }
}

// Round 5
// 345.785 us; speedup vs baseline: 2.8424x; 1.0583x over previous
//
#include <hip/hip_runtime.h>
#include <cstddef>

#define NB 16
#define NM 512
#define NHID 256
#define NTOPK 32
#define NROWS (NB*NM)
#define NLAYER 4

typedef unsigned short ushort_t;
typedef __attribute__((ext_vector_type(8))) short short8;
typedef __attribute__((ext_vector_type(4))) float f32x4;

// MFMA A-fragment LDS layout with bank-decorrelating XOR:
// element (row 0..15, byte-group c8=col>>3) lives at block ks=c8>>2,
// slot = (c8&3)*16 + (row ^ ks). Reader lane l for k-slice ks reads
// slot (l>>4)*16 + ((l&15) ^ ks). Store/read use the same involution.
#define FRAG_OFF(row, c8) (((c8) >> 2) * 1024 + ((((c8) & 3) << 4) + (((row) & 15) ^ ((c8) >> 2))) * 16)
#define FRAG_RD(ks, lane) ((ks) * 1024 + ((((lane) >> 4) << 4) + (((lane) & 15) ^ (ks))) * 16)

__device__ __forceinline__ float mish_f(float t) {
    float sp = (t > 20.0f) ? t : log1pf(__expf(t));
    return t * tanhf(sp);
}
__device__ __forceinline__ ushort_t f2b(float f) {   // fp32 -> bf16 RNE
    unsigned u = __float_as_uint(f);
    return (ushort_t)((u + 0x7FFFu + ((u >> 16) & 1u)) >> 16);
}
__device__ __forceinline__ float b2f(ushort_t h) {
    return __uint_as_float(((unsigned)h) << 16);
}

// ---------------- top-k: ballot bisection, one wave per row ------------------
__global__ __launch_bounds__(256) void topk_kernel(const float* __restrict__ edge,
                                                   int* __restrict__ tidx,
                                                   float* __restrict__ tw) {
    const int lane = threadIdx.x & 63, w = threadIdx.x >> 6;
    const int row = blockIdx.x * 4 + w;
    const float* er = edge + (size_t)row * NM;
    float v[8]; unsigned u[8];
    #pragma unroll
    for (int s = 0; s < 8; ++s) { v[s] = er[s * 64 + lane]; u[s] = __float_as_uint(v[s]); }
    unsigned T = 0;
    for (int bit = 31; bit >= 0; --bit) {
        unsigned Tc = T | (1u << bit);
        int c = 0;
        #pragma unroll
        for (int s = 0; s < 8; ++s) c += (int)__popcll(__ballot(u[s] >= Tc));
        if (c >= NTOPK) T = Tc;
    }
    int cgt = 0;
    #pragma unroll
    for (int s = 0; s < 8; ++s) cgt += (int)__popcll(__ballot(u[s] > T));
    const int extra = NTOPK - cgt;
    float psum = 0.f;
    #pragma unroll
    for (int s = 0; s < 8; ++s) psum += (u[s] > T) ? v[s] : 0.f;
    psum += __shfl_xor(psum, 1); psum += __shfl_xor(psum, 2); psum += __shfl_xor(psum, 4);
    psum += __shfl_xor(psum, 8); psum += __shfl_xor(psum, 16); psum += __shfl_xor(psum, 32);
    const float ssum = psum + (float)extra * __uint_as_float(T);
    const float den = ssum + 1e-5f;
    const unsigned long long lmask = (1ull << lane) - 1ull;
    int base = 0, eqbase = 0;
    #pragma unroll
    for (int s = 0; s < 8; ++s) {
        bool gt = (u[s] > T), eq = (u[s] == T);
        unsigned long long meq = __ballot(eq);
        int eqrank = eqbase + (int)__popcll(meq & lmask);
        bool sel = gt || (eq && eqrank < extra);
        unsigned long long msel = __ballot(sel);
        if (sel) {
            int pos = base + (int)__popcll(msel & lmask);
            tidx[row * NTOPK + pos] = s * 64 + lane;
            tw[row * NTOPK + pos] = v[s] / den;
        }
        base += (int)__popcll(msel);
        eqbase += (int)__popcll(meq);
    }
}

// ---------------- weight conversion into MFMA-fragment layout ----------------
__global__ __launch_bounds__(256) void wconv_kernel(const float* __restrict__ attnW,
                                                    const float* __restrict__ ffnW,
                                                    ushort_t* __restrict__ wb) {
    int t = blockIdx.x * 256 + threadIdx.x;      // 196608 threads
    int frag = t >> 9, r = t & 511;
    int ks = r >> 6, l = r & 63;
    const float* src;
    if (frag < 256) src = attnW + ((size_t)(frag >> 6) * 1024 + (frag & 63) * 16 + (l & 15)) * 256;
    else { int fi = frag - 256; src = ffnW + ((size_t)(fi >> 5) * 512 + (fi & 31) * 16 + (l & 15)) * 256; }
    src += ks * 32 + (l >> 4) * 8;
    short8 o;
    #pragma unroll
    for (int j = 0; j < 8; ++j) o[j] = (short)f2b(src[j]);
    *(short8*)(wb + (size_t)t * 8) = o;
}

// ---------------- K1: LN1 + fused QKV GEMM (per 16-row block) ----------------
__global__ __launch_bounds__(256) void k1_ln_qkv(const float* __restrict__ xin,
                                                 float* __restrict__ x,
                                                 float* __restrict__ q,
                                                 ushort_t* __restrict__ kvb,
                                                 const ushort_t* __restrict__ wf,
                                                 const float* __restrict__ bias,
                                                 const float* __restrict__ ga,
                                                 const float* __restrict__ gb) {
    __shared__ __align__(16) char af[8192];      // A-fragments, 16 rows x 256 cols bf16
    const int tid = threadIdx.x, lane = tid & 63, w = tid >> 6;
    const int bm = blockIdx.x * 16;
    {
        const int rr = lane >> 4, c16 = (lane & 15) << 4;
        const int ri = (w << 2) + rr;
        const float* xr = xin + (size_t)(bm + ri) * NHID + c16;
        f32x4 v0 = *(const f32x4*)(xr);
        f32x4 v1 = *(const f32x4*)(xr + 4);
        f32x4 v2 = *(const f32x4*)(xr + 8);
        f32x4 v3 = *(const f32x4*)(xr + 12);
        float s = 0.f;
        #pragma unroll
        for (int k = 0; k < 4; ++k) s += v0[k] + v1[k] + v2[k] + v3[k];
        s += __shfl_xor(s, 1); s += __shfl_xor(s, 2); s += __shfl_xor(s, 4); s += __shfl_xor(s, 8);
        float mean = s * (1.0f / NHID);
        float vr = 0.f;
        #pragma unroll
        for (int k = 0; k < 4; ++k) {
            float d0 = v0[k]-mean, d1 = v1[k]-mean, d2 = v2[k]-mean, d3 = v3[k]-mean;
            vr += d0*d0 + d1*d1 + d2*d2 + d3*d3;
        }
        vr += __shfl_xor(vr, 1); vr += __shfl_xor(vr, 2); vr += __shfl_xor(vr, 4); vr += __shfl_xor(vr, 8);
        vr *= (1.0f / (NHID - 1));
        float rs = 1.0f / (sqrtf(vr) + 1e-6f);
        f32x4 g0 = *(const f32x4*)(ga + c16), g1 = *(const f32x4*)(ga + c16 + 4);
        f32x4 g2 = *(const f32x4*)(ga + c16 + 8), g3 = *(const f32x4*)(ga + c16 + 12);
        f32x4 h0 = *(const f32x4*)(gb + c16), h1 = *(const f32x4*)(gb + c16 + 4);
        f32x4 h2 = *(const f32x4*)(gb + c16 + 8), h3 = *(const f32x4*)(gb + c16 + 12);
        f32x4 o0, o1, o2, o3;
        #pragma unroll
        for (int k = 0; k < 4; ++k) {
            o0[k] = g0[k]*(v0[k]-mean)*rs + h0[k];
            o1[k] = g1[k]*(v1[k]-mean)*rs + h1[k];
            o2[k] = g2[k]*(v2[k]-mean)*rs + h2[k];
            o3[k] = g3[k]*(v3[k]-mean)*rs + h3[k];
        }
        float* xw = x + (size_t)(bm + ri) * NHID + c16;
        *(f32x4*)(xw) = o0; *(f32x4*)(xw + 4) = o1;
        *(f32x4*)(xw + 8) = o2; *(f32x4*)(xw + 12) = o3;
        short8 p0, p1;
        #pragma unroll
        for (int k = 0; k < 4; ++k) {
            p0[k] = (short)f2b(o0[k]); p0[4+k] = (short)f2b(o1[k]);
            p1[k] = (short)f2b(o2[k]); p1[4+k] = (short)f2b(o3[k]);
        }
        int c8 = (lane & 15) * 2;
        *(short8*)(af + FRAG_OFF(ri, c8)) = p0;
        *(short8*)(af + FRAG_OFF(ri, c8 + 1)) = p1;
    }
    __syncthreads();
    short8 a[8];
    #pragma unroll
    for (int ks = 0; ks < 8; ++ks) a[ks] = *(const short8*)(af + FRAG_RD(ks, lane));
    #pragma unroll
    for (int g = 0; g < 6; ++g) {
        const int col0 = g * 128 + w * 32;
        f32x4 acc0 = {}, acc1 = {};
        const ushort_t* bp0 = wf + ((size_t)((col0 >> 4) * 8) * 64 + lane) * 8;
        const ushort_t* bp1 = bp0 + 4096;
        #pragma unroll
        for (int ks = 0; ks < 8; ++ks) {
            short8 b0 = *(const short8*)(bp0 + ks * 512);
            short8 b1 = *(const short8*)(bp1 + ks * 512);
            acc0 = __builtin_amdgcn_mfma_f32_16x16x32_bf16(a[ks], b0, acc0, 0, 0, 0);
            acc1 = __builtin_amdgcn_mfma_f32_16x16x32_bf16(a[ks], b1, acc1, 0, 0, 0);
        }
        const int rbase = bm + (lane >> 4) * 4;
        #pragma unroll
        for (int ni = 0; ni < 2; ++ni) {
            int col = col0 + ni * 16 + (lane & 15);
            float bv = bias[col];
            f32x4 A = ni ? acc1 : acc0;
            #pragma unroll
            for (int j = 0; j < 4; ++j) {
                int row = rbase + j;
                float vv = A[j] + bv;
                if (col < 256) q[(size_t)row * 256 + col] = vv;
                else kvb[(size_t)row * 512 + (col - 256)] = f2b(vv);
            }
        }
    }
}

// ---------------- K2: vsum + attn + Wo + LN2 + FFN1 + FFN2 (per 32 rows) -----
// Grid swizzled so each XCD (bid%8) owns 2 batches -> KV gather stays in its L2.
__global__ __launch_bounds__(512) void k2_attn_ffn(float* __restrict__ x,
                                                   const float* __restrict__ q,
                                                   const ushort_t* __restrict__ kvb,
                                                   const int* __restrict__ tidx,
                                                   const float* __restrict__ tw,
                                                   const int* __restrict__ msk,
                                                   const ushort_t* __restrict__ wfo,
                                                   const ushort_t* __restrict__ wf1,
                                                   const ushort_t* __restrict__ wf2,
                                                   const float* __restrict__ bo,
                                                   const float* __restrict__ b1,
                                                   const float* __restrict__ b2,
                                                   const float* __restrict__ ga,
                                                   const float* __restrict__ gb) {
    __shared__ __align__(16) float regA[8192];   // 32KB: ph0 vsum partials; ph3+ x2 tile
    __shared__ __align__(16) char regB[16384];   // A-frag (attn-out, then xc)
    __shared__ __align__(16) char regC[16384];   // sidx/sws/vsumf, then h-frag
    const int tid = threadIdx.x, lane = tid & 63, w = tid >> 6;
    const int wid = (blockIdx.x & 7) * 32 + (blockIdx.x >> 3);   // XCD-affinity swizzle
    const int R0 = wid * 32, bb = R0 >> 9;
    int* sidx = (int*)regC;
    float* sws = (float*)(regC + 4096);
    float* vsumf = (float*)(regC + 8192);
    // ---- ph0a: V column-sum partials (wave w sums 64 rows of batch bb)
    {
        const ushort_t* vb = kvb + ((size_t)(bb * NM + w * 64)) * 512 + 256 + lane * 4;
        float s0 = 0.f, s1 = 0.f, s2 = 0.f, s3 = 0.f;
        #pragma unroll 8
        for (int r = 0; r < 64; ++r) {
            const ushort_t* p = vb + (size_t)r * 512;
            s0 += b2f(p[0]); s1 += b2f(p[1]); s2 += b2f(p[2]); s3 += b2f(p[3]);
        }
        regA[w * 256 + lane * 4 + 0] = s0; regA[w * 256 + lane * 4 + 1] = s1;
        regA[w * 256 + lane * 4 + 2] = s2; regA[w * 256 + lane * 4 + 3] = s3;
    }
    // ---- ph1: topk lists for 32 rows (mask folded into sign bit)
    for (int i = tid; i < 1024; i += 512) {
        int r = i >> 5;
        int nb = tidx[(size_t)(R0 + r) * NTOPK + (i & 31)];
        float wv = tw[(size_t)(R0 + r) * NTOPK + (i & 31)] * 0.17677669529663687f;
        sidx[i] = (msk[bb * NM + nb] == 0) ? (nb | (int)0x80000000) : nb;
        sws[i] = wv;
    }
    __syncthreads();
    // ---- ph0b: reduce vsum partials
    if (tid < 256) {
        float s = 0.f;
        #pragma unroll
        for (int w8 = 0; w8 < 8; ++w8) s += regA[w8 * 256 + tid];
        vsumf[tid] = s;
    }
    __syncthreads();
    // ---- ph2: sparse attention; lane = (row rr, head h, half)
    {
        const int rr = lane >> 4;
        const int rl = (w << 2) + rr;            // local row 0..31
        const int row = R0 + rl;
        const int cbase = ((lane >> 1) & 7) * 32 + (lane & 1) * 16;
        const float* qp = q + (size_t)row * NHID + cbase;
        float qv[16];
        {
            f32x4 q0 = *(const f32x4*)(qp), q1 = *(const f32x4*)(qp + 4);
            f32x4 q2 = *(const f32x4*)(qp + 8), q3 = *(const f32x4*)(qp + 12);
            #pragma unroll
            for (int k = 0; k < 4; ++k) { qv[k]=q0[k]; qv[4+k]=q1[k]; qv[8+k]=q2[k]; qv[12+k]=q3[k]; }
        }
        float accv[16];
        #pragma unroll
        for (int k = 0; k < 16; ++k) accv[k] = 0.f;
        float den = 0.f;
        for (int j = 0; j < NTOPK; ++j) {
            int raw = sidx[rl * 32 + j];
            float swv = sws[rl * 32 + j];
            int nb = raw & 511;
            const ushort_t* kp = kvb + ((size_t)(bb * NM + nb)) * 512 + cbase;
            short8 kA = *(const short8*)(kp);
            short8 kB = *(const short8*)(kp + 8);
            short8 vA = *(const short8*)(kp + 256);
            short8 vB = *(const short8*)(kp + 264);
            float p = 0.f;
            #pragma unroll
            for (int t = 0; t < 8; ++t) p += qv[t] * b2f((ushort_t)kA[t]);
            #pragma unroll
            for (int t = 0; t < 8; ++t) p += qv[8 + t] * b2f((ushort_t)kB[t]);
            p += __shfl_xor(p, 1);
            float sarg = (raw < 0) ? -1e12f : p;
            float e = __expf(sarg * swv);
            float em1 = e - 1.0f;
            den += em1;
            #pragma unroll
            for (int t = 0; t < 8; ++t) accv[t] += em1 * b2f((ushort_t)vA[t]);
            #pragma unroll
            for (int t = 0; t < 8; ++t) accv[8 + t] += em1 * b2f((ushort_t)vB[t]);
        }
        float rden = 1.0f / (den + 512.0f);
        short8 p0, p1;
        #pragma unroll
        for (int t = 0; t < 8; ++t) {
            p0[t] = (short)f2b((accv[t] + vsumf[cbase + t]) * rden);
            p1[t] = (short)f2b((accv[8 + t] + vsumf[cbase + 8 + t]) * rden);
        }
        const int rb = rl >> 4, rif = rl & 15;
        int c8 = cbase >> 3;
        *(short8*)(regB + rb * 8192 + FRAG_OFF(rif, c8)) = p0;
        *(short8*)(regB + rb * 8192 + FRAG_OFF(rif, c8 + 1)) = p1;
    }
    __syncthreads();
    // ---- ph3: Wo GEMM + mish + residual(x) -> regA (x2 tile)
    {
        const int col0 = w * 32;
        f32x4 acc[2][2] = {};
        const ushort_t* bp0 = wfo + ((size_t)((col0 >> 4) * 8) * 64 + lane) * 8;
        const ushort_t* bp1 = bp0 + 4096;
        #pragma unroll
        for (int ks = 0; ks < 8; ++ks) {
            short8 a0 = *(const short8*)(regB + FRAG_RD(ks, lane));
            short8 a1 = *(const short8*)(regB + 8192 + FRAG_RD(ks, lane));
            short8 b0 = *(const short8*)(bp0 + ks * 512);
            short8 b1 = *(const short8*)(bp1 + ks * 512);
            acc[0][0] = __builtin_amdgcn_mfma_f32_16x16x32_bf16(a0, b0, acc[0][0], 0, 0, 0);
            acc[0][1] = __builtin_amdgcn_mfma_f32_16x16x32_bf16(a0, b1, acc[0][1], 0, 0, 0);
            acc[1][0] = __builtin_amdgcn_mfma_f32_16x16x32_bf16(a1, b0, acc[1][0], 0, 0, 0);
            acc[1][1] = __builtin_amdgcn_mfma_f32_16x16x32_bf16(a1, b1, acc[1][1], 0, 0, 0);
        }
        #pragma unroll
        for (int mi = 0; mi < 2; ++mi) {
            #pragma unroll
            for (int ni = 0; ni < 2; ++ni) {
                int col = col0 + ni * 16 + (lane & 15);
                float bv = bo[col];
                #pragma unroll
                for (int j = 0; j < 4; ++j) {
                    int row = mi * 16 + (lane >> 4) * 4 + j;
                    float v = mish_f(acc[mi][ni][j] + bv) + x[(size_t)(R0 + row) * NHID + col];
                    regA[row * 256 + col] = v;
                }
            }
        }
    }
    __syncthreads();
    // ---- ph4: LN2 on regA (in place) + frag -> regB
    {
        const int rr = lane >> 4, c16 = (lane & 15) << 4;
        const int rl = (w << 2) + rr;
        float* xr = regA + rl * 256 + c16;
        f32x4 v0 = *(const f32x4*)(xr);
        f32x4 v1 = *(const f32x4*)(xr + 4);
        f32x4 v2 = *(const f32x4*)(xr + 8);
        f32x4 v3 = *(const f32x4*)(xr + 12);
        float s = 0.f;
        #pragma unroll
        for (int k = 0; k < 4; ++k) s += v0[k] + v1[k] + v2[k] + v3[k];
        s += __shfl_xor(s, 1); s += __shfl_xor(s, 2); s += __shfl_xor(s, 4); s += __shfl_xor(s, 8);
        float mean = s * (1.0f / NHID);
        float vr = 0.f;
        #pragma unroll
        for (int k = 0; k < 4; ++k) {
            float d0 = v0[k]-mean, d1 = v1[k]-mean, d2 = v2[k]-mean, d3 = v3[k]-mean;
            vr += d0*d0 + d1*d1 + d2*d2 + d3*d3;
        }
        vr += __shfl_xor(vr, 1); vr += __shfl_xor(vr, 2); vr += __shfl_xor(vr, 4); vr += __shfl_xor(vr, 8);
        vr *= (1.0f / (NHID - 1));
        float rs = 1.0f / (sqrtf(vr) + 1e-6f);
        f32x4 g0 = *(const f32x4*)(ga + c16), g1 = *(const f32x4*)(ga + c16 + 4);
        f32x4 g2 = *(const f32x4*)(ga + c16 + 8), g3 = *(const f32x4*)(ga + c16 + 12);
        f32x4 h0 = *(const f32x4*)(gb + c16), h1 = *(const f32x4*)(gb + c16 + 4);
        f32x4 h2 = *(const f32x4*)(gb + c16 + 8), h3 = *(const f32x4*)(gb + c16 + 12);
        f32x4 o0, o1, o2, o3;
        #pragma unroll
        for (int k = 0; k < 4; ++k) {
            o0[k] = g0[k]*(v0[k]-mean)*rs + h0[k];
            o1[k] = g1[k]*(v1[k]-mean)*rs + h1[k];
            o2[k] = g2[k]*(v2[k]-mean)*rs + h2[k];
            o3[k] = g3[k]*(v3[k]-mean)*rs + h3[k];
        }
        *(f32x4*)(xr) = o0; *(f32x4*)(xr + 4) = o1;
        *(f32x4*)(xr + 8) = o2; *(f32x4*)(xr + 12) = o3;
        short8 p0, p1;
        #pragma unroll
        for (int k = 0; k < 4; ++k) {
            p0[k] = (short)f2b(o0[k]); p0[4+k] = (short)f2b(o1[k]);
            p1[k] = (short)f2b(o2[k]); p1[4+k] = (short)f2b(o3[k]);
        }
        const int rb = rl >> 4, rif = rl & 15;
        int c8 = (lane & 15) * 2;
        *(short8*)(regB + rb * 8192 + FRAG_OFF(rif, c8)) = p0;
        *(short8*)(regB + rb * 8192 + FRAG_OFF(rif, c8 + 1)) = p1;
    }
    __syncthreads();
    // ---- ph5: FFN1 (mish) -> h-frag in regC
    {
        const int col0 = w * 32;
        f32x4 acc[2][2] = {};
        const ushort_t* bp0 = wf1 + ((size_t)((col0 >> 4) * 8) * 64 + lane) * 8;
        const ushort_t* bp1 = bp0 + 4096;
        #pragma unroll
        for (int ks = 0; ks < 8; ++ks) {
            short8 a0 = *(const short8*)(regB + FRAG_RD(ks, lane));
            short8 a1 = *(const short8*)(regB + 8192 + FRAG_RD(ks, lane));
            short8 b0 = *(const short8*)(bp0 + ks * 512);
            short8 b1 = *(const short8*)(bp1 + ks * 512);
            acc[0][0] = __builtin_amdgcn_mfma_f32_16x16x32_bf16(a0, b0, acc[0][0], 0, 0, 0);
            acc[0][1] = __builtin_amdgcn_mfma_f32_16x16x32_bf16(a0, b1, acc[0][1], 0, 0, 0);
            acc[1][0] = __builtin_amdgcn_mfma_f32_16x16x32_bf16(a1, b0, acc[1][0], 0, 0, 0);
            acc[1][1] = __builtin_amdgcn_mfma_f32_16x16x32_bf16(a1, b1, acc[1][1], 0, 0, 0);
        }
        __syncthreads();   // regC topk/vsum data dead; safe to overwrite
        #pragma unroll
        for (int mi = 0; mi < 2; ++mi) {
            #pragma unroll
            for (int ni = 0; ni < 2; ++ni) {
                int col = col0 + ni * 16 + (lane & 15);
                float bv = b1[col];
                int c8 = col >> 3;
                #pragma unroll
                for (int j = 0; j < 4; ++j) {
                    int row = mi * 16 + (lane >> 4) * 4 + j;
                    float v = mish_f(acc[mi][ni][j] + bv);
                    *(ushort_t*)(regC + (row >> 4) * 8192 + FRAG_OFF(row & 15, c8)
                                 + (col & 7) * 2) = f2b(v);
                }
            }
        }
    }
    __syncthreads();
    // ---- ph6: FFN2 (mish) + residual(regA) -> global x
    {
        const int col0 = w * 32;
        f32x4 acc[2][2] = {};
        const ushort_t* bp0 = wf2 + ((size_t)((col0 >> 4) * 8) * 64 + lane) * 8;
        const ushort_t* bp1 = bp0 + 4096;
        #pragma unroll
        for (int ks = 0; ks < 8; ++ks) {
            short8 a0 = *(const short8*)(regC + FRAG_RD(ks, lane));
            short8 a1 = *(const short8*)(regC + 8192 + FRAG_RD(ks, lane));
            short8 b0 = *(const short8*)(bp0 + ks * 512);
            short8 b1 = *(const short8*)(bp1 + ks * 512);
            acc[0][0] = __builtin_amdgcn_mfma_f32_16x16x32_bf16(a0, b0, acc[0][0], 0, 0, 0);
            acc[0][1] = __builtin_amdgcn_mfma_f32_16x16x32_bf16(a0, b1, acc[0][1], 0, 0, 0);
            acc[1][0] = __builtin_amdgcn_mfma_f32_16x16x32_bf16(a1, b0, acc[1][0], 0, 0, 0);
            acc[1][1] = __builtin_amdgcn_mfma_f32_16x16x32_bf16(a1, b1, acc[1][1], 0, 0, 0);
        }
        #pragma unroll
        for (int mi = 0; mi < 2; ++mi) {
            #pragma unroll
            for (int ni = 0; ni < 2; ++ni) {
                int col = col0 + ni * 16 + (lane & 15);
                float bv = b2[col];
                #pragma unroll
                for (int j = 0; j < 4; ++j) {
                    int row = mi * 16 + (lane >> 4) * 4 + j;
                    float v = mish_f(acc[mi][ni][j] + bv) + regA[row * 256 + col];
                    x[(size_t)(R0 + row) * NHID + col] = v;
                }
            }
        }
    }
}

extern "C" void kernel_launch(void* const* d_in, const int* in_sizes, int n_in,
                              void* d_out, int out_size, void* d_ws, size_t ws_size,
                              hipStream_t stream) {
    (void)in_sizes; (void)n_in; (void)out_size; (void)ws_size;
    const float* node  = (const float*)d_in[0];
    const float* edge  = (const float*)d_in[1];
    const int*   msk   = (const int*)d_in[2];
    const float* attnW = (const float*)d_in[3];
    const float* attnB = (const float*)d_in[4];
    const float* ffnW  = (const float*)d_in[5];
    const float* ffnB  = (const float*)d_in[6];
    const float* lna   = (const float*)d_in[7];
    const float* lnb   = (const float*)d_in[8];

    float* x = (float*)d_out;                       // running activation [8192,256] fp32
    float* wsf = (float*)d_ws;
    // workspace: 5,505,024 floats = 21 MB
    float*    q    = wsf;                           // [8192,256] fp32
    ushort_t* kvb  = (ushort_t*)(wsf + 2097152);    // [8192,512] bf16
    ushort_t* wb   = (ushort_t*)(wsf + 4194304);    // 1,572,864 bf16 frag weights
    float*    tw   = wsf + 4980736;                 // [8192,32]
    int*      tidx = (int*)(wsf + 5242880);         // [8192,32]

    wconv_kernel<<<768, 256, 0, stream>>>(attnW, ffnW, wb);
    topk_kernel<<<2048, 256, 0, stream>>>(edge, tidx, tw);

    for (int l = 0; l < NLAYER; ++l) {
        k1_ln_qkv<<<512, 256, 0, stream>>>(
            l == 0 ? node : x, x, q, kvb,
            wb + (size_t)(l * 64) * 4096, attnB + (size_t)l * 1024, lna, lnb);
        k2_attn_ffn<<<256, 512, 0, stream>>>(
            x, q, kvb, tidx, tw, msk,
            wb + (size_t)(l * 64 + 48) * 4096,
            wb + (size_t)(256 + l * 32) * 4096,
            wb + (size_t)(256 + l * 32 + 16) * 4096,
            attnB + (size_t)l * 1024 + 768,
            ffnB + (size_t)l * 512,
            ffnB + (size_t)l * 512 + 256,
            lna, lnb);
    }
}

// Round 6
// 234.195 us; speedup vs baseline: 4.1968x; 1.4765x over previous
//
#include <hip/hip_runtime.h>
#include <cstddef>

#define NB 16
#define NM 512
#define NHID 256
#define NTOPK 32
#define NROWS (NB*NM)
#define NLAYER 4
#define XPITCH 260   // padded LDS row stride (floats) for the fp32 x-tile

typedef unsigned short ushort_t;
typedef __attribute__((ext_vector_type(8))) short short8;
typedef __attribute__((ext_vector_type(4))) float f32x4;

// MFMA A-fragment LDS layout with bank-decorrelating XOR (verified round 5).
#define FRAG_OFF(row, c8) (((c8) >> 2) * 1024 + ((((c8) & 3) << 4) + (((row) & 15) ^ ((c8) >> 2))) * 16)
#define FRAG_RD(ks, lane) ((ks) * 1024 + ((((lane) >> 4) << 4) + (((lane) & 15) ^ (ks))) * 16)

// mish(v) = v*tanh(softplus(v)) = v*(t^2+2t)/(t^2+2t+2), t=e^v  (1 transcendental)
__device__ __forceinline__ float mish_f(float v) {
    if (v > 20.0f) return v;
    float t = __expf(v);
    float u = t * (t + 2.0f);
    return v * (u / (u + 2.0f));
}
__device__ __forceinline__ ushort_t f2b(float f) {   // fp32 -> bf16 RNE
    unsigned u = __float_as_uint(f);
    return (ushort_t)((u + 0x7FFFu + ((u >> 16) & 1u)) >> 16);
}
__device__ __forceinline__ float b2f(ushort_t h) {
    return __uint_as_float(((unsigned)h) << 16);
}

// ---------------- top-k: ballot bisection, one wave per row ------------------
__global__ __launch_bounds__(256) void topk_kernel(const float* __restrict__ edge,
                                                   int* __restrict__ tidx,
                                                   float* __restrict__ tw) {
    const int lane = threadIdx.x & 63, w = threadIdx.x >> 6;
    const int row = blockIdx.x * 4 + w;
    const float* er = edge + (size_t)row * NM;
    float v[8]; unsigned u[8];
    #pragma unroll
    for (int s = 0; s < 8; ++s) { v[s] = er[s * 64 + lane]; u[s] = __float_as_uint(v[s]); }
    unsigned T = 0;
    for (int bit = 31; bit >= 0; --bit) {
        unsigned Tc = T | (1u << bit);
        int c = 0;
        #pragma unroll
        for (int s = 0; s < 8; ++s) c += (int)__popcll(__ballot(u[s] >= Tc));
        if (c >= NTOPK) T = Tc;
    }
    int cgt = 0;
    #pragma unroll
    for (int s = 0; s < 8; ++s) cgt += (int)__popcll(__ballot(u[s] > T));
    const int extra = NTOPK - cgt;
    float psum = 0.f;
    #pragma unroll
    for (int s = 0; s < 8; ++s) psum += (u[s] > T) ? v[s] : 0.f;
    psum += __shfl_xor(psum, 1); psum += __shfl_xor(psum, 2); psum += __shfl_xor(psum, 4);
    psum += __shfl_xor(psum, 8); psum += __shfl_xor(psum, 16); psum += __shfl_xor(psum, 32);
    const float ssum = psum + (float)extra * __uint_as_float(T);
    const float den = ssum + 1e-5f;
    const unsigned long long lmask = (1ull << lane) - 1ull;
    int base = 0, eqbase = 0;
    #pragma unroll
    for (int s = 0; s < 8; ++s) {
        bool gt = (u[s] > T), eq = (u[s] == T);
        unsigned long long meq = __ballot(eq);
        int eqrank = eqbase + (int)__popcll(meq & lmask);
        bool sel = gt || (eq && eqrank < extra);
        unsigned long long msel = __ballot(sel);
        if (sel) {
            int pos = base + (int)__popcll(msel & lmask);
            tidx[row * NTOPK + pos] = s * 64 + lane;
            tw[row * NTOPK + pos] = v[s] / den;
        }
        base += (int)__popcll(msel);
        eqbase += (int)__popcll(meq);
    }
}

// ---------------- weight conversion into MFMA-fragment layout ----------------
__global__ __launch_bounds__(256) void wconv_kernel(const float* __restrict__ attnW,
                                                    const float* __restrict__ ffnW,
                                                    ushort_t* __restrict__ wb) {
    int t = blockIdx.x * 256 + threadIdx.x;      // 196608 threads
    int frag = t >> 9, r = t & 511;
    int ks = r >> 6, l = r & 63;
    const float* src;
    if (frag < 256) src = attnW + ((size_t)(frag >> 6) * 1024 + (frag & 63) * 16 + (l & 15)) * 256;
    else { int fi = frag - 256; src = ffnW + ((size_t)(fi >> 5) * 512 + (fi & 31) * 16 + (l & 15)) * 256; }
    src += ks * 32 + (l >> 4) * 8;
    short8 o;
    #pragma unroll
    for (int j = 0; j < 8; ++j) o[j] = (short)f2b(src[j]);
    *(short8*)(wb + (size_t)t * 8) = o;
}

// ---------------- K1: LN1 + QKV GEMM, column-split over blockIdx.y -----------
__global__ __launch_bounds__(256) void k1_ln_qkv(const float* __restrict__ xin,
                                                 float* __restrict__ x,
                                                 float* __restrict__ q,
                                                 ushort_t* __restrict__ kvb,
                                                 const ushort_t* __restrict__ wf,
                                                 const float* __restrict__ bias,
                                                 const float* __restrict__ ga,
                                                 const float* __restrict__ gb) {
    __shared__ __align__(16) char af[8192];      // A-fragments, 16 rows x 256 cols bf16
    const int tid = threadIdx.x, lane = tid & 63, w = tid >> 6;
    const int bx = blockIdx.x;
    const int wid = (bx & 7) * 64 + (bx >> 3);   // XCD affinity matches k2
    const int bm = wid * 16;
    const int zb = blockIdx.y;                   // column half (0: QK-, 1: -VV)
    {
        const int rr = lane >> 4, c16 = (lane & 15) << 4;
        const int ri = (w << 2) + rr;
        const float* xr = xin + (size_t)(bm + ri) * NHID + c16;
        f32x4 v0 = *(const f32x4*)(xr);
        f32x4 v1 = *(const f32x4*)(xr + 4);
        f32x4 v2 = *(const f32x4*)(xr + 8);
        f32x4 v3 = *(const f32x4*)(xr + 12);
        float s = 0.f;
        #pragma unroll
        for (int k = 0; k < 4; ++k) s += v0[k] + v1[k] + v2[k] + v3[k];
        s += __shfl_xor(s, 1); s += __shfl_xor(s, 2); s += __shfl_xor(s, 4); s += __shfl_xor(s, 8);
        float mean = s * (1.0f / NHID);
        float vr = 0.f;
        #pragma unroll
        for (int k = 0; k < 4; ++k) {
            float d0 = v0[k]-mean, d1 = v1[k]-mean, d2 = v2[k]-mean, d3 = v3[k]-mean;
            vr += d0*d0 + d1*d1 + d2*d2 + d3*d3;
        }
        vr += __shfl_xor(vr, 1); vr += __shfl_xor(vr, 2); vr += __shfl_xor(vr, 4); vr += __shfl_xor(vr, 8);
        vr *= (1.0f / (NHID - 1));
        float rs = 1.0f / (sqrtf(vr) + 1e-6f);
        f32x4 g0 = *(const f32x4*)(ga + c16), g1 = *(const f32x4*)(ga + c16 + 4);
        f32x4 g2 = *(const f32x4*)(ga + c16 + 8), g3 = *(const f32x4*)(ga + c16 + 12);
        f32x4 h0 = *(const f32x4*)(gb + c16), h1 = *(const f32x4*)(gb + c16 + 4);
        f32x4 h2 = *(const f32x4*)(gb + c16 + 8), h3 = *(const f32x4*)(gb + c16 + 12);
        f32x4 o0, o1, o2, o3;
        #pragma unroll
        for (int k = 0; k < 4; ++k) {
            o0[k] = g0[k]*(v0[k]-mean)*rs + h0[k];
            o1[k] = g1[k]*(v1[k]-mean)*rs + h1[k];
            o2[k] = g2[k]*(v2[k]-mean)*rs + h2[k];
            o3[k] = g3[k]*(v3[k]-mean)*rs + h3[k];
        }
        if (zb == 0) {
            float* xw = x + (size_t)(bm + ri) * NHID + c16;
            *(f32x4*)(xw) = o0; *(f32x4*)(xw + 4) = o1;
            *(f32x4*)(xw + 8) = o2; *(f32x4*)(xw + 12) = o3;
        }
        short8 p0, p1;
        #pragma unroll
        for (int k = 0; k < 4; ++k) {
            p0[k] = (short)f2b(o0[k]); p0[4+k] = (short)f2b(o1[k]);
            p1[k] = (short)f2b(o2[k]); p1[4+k] = (short)f2b(o3[k]);
        }
        int c8 = (lane & 15) * 2;
        *(short8*)(af + FRAG_OFF(ri, c8)) = p0;
        *(short8*)(af + FRAG_OFF(ri, c8 + 1)) = p1;
    }
    __syncthreads();
    short8 a[8];
    #pragma unroll
    for (int ks = 0; ks < 8; ++ks) a[ks] = *(const short8*)(af + FRAG_RD(ks, lane));
    #pragma unroll
    for (int gi = 0; gi < 3; ++gi) {
        const int col0 = (zb * 3 + gi) * 128 + w * 32;
        f32x4 acc0 = {}, acc1 = {};
        const ushort_t* bp0 = wf + ((size_t)((col0 >> 4) * 8) * 64 + lane) * 8;
        const ushort_t* bp1 = bp0 + 4096;
        #pragma unroll
        for (int ks = 0; ks < 8; ++ks) {
            short8 b0 = *(const short8*)(bp0 + ks * 512);
            short8 b1 = *(const short8*)(bp1 + ks * 512);
            acc0 = __builtin_amdgcn_mfma_f32_16x16x32_bf16(a[ks], b0, acc0, 0, 0, 0);
            acc1 = __builtin_amdgcn_mfma_f32_16x16x32_bf16(a[ks], b1, acc1, 0, 0, 0);
        }
        const int rbase = bm + (lane >> 4) * 4;
        #pragma unroll
        for (int ni = 0; ni < 2; ++ni) {
            int col = col0 + ni * 16 + (lane & 15);
            float bv = bias[col];
            f32x4 A = ni ? acc1 : acc0;
            #pragma unroll
            for (int j = 0; j < 4; ++j) {
                int row = rbase + j;
                float vv = A[j] + bv;
                if (col < 256) q[(size_t)row * 256 + col] = vv;
                else kvb[(size_t)row * 512 + (col - 256)] = f2b(vv);
            }
        }
    }
}

// ---------------- V column-sum partials: part[b][s][c] ----------------------
__global__ __launch_bounds__(256) void vpart_kernel(const ushort_t* __restrict__ kv,
                                                    float* __restrict__ part) {
    const int b = blockIdx.x, s = blockIdx.y, t = threadIdx.x;
    float acc = 0.f;
    const ushort_t* base = kv + ((size_t)(b * NM + s * 64)) * 512 + 256 + t;
    #pragma unroll 8
    for (int n = 0; n < 64; ++n) acc += b2f(base[(size_t)n * 512]);
    part[((size_t)(b * 8 + s)) * NHID + t] = acc;
}

// ---------------- K2: attn + Wo + LN2 + FFN1 + FFN2 (16 rows, 256 thr) -------
__global__ __launch_bounds__(256) void k2_attn_ffn(float* __restrict__ x,
                                                   const float* __restrict__ q,
                                                   const ushort_t* __restrict__ kvb,
                                                   const int* __restrict__ tidx,
                                                   const float* __restrict__ tw,
                                                   const int* __restrict__ msk,
                                                   const float* __restrict__ part,
                                                   const ushort_t* __restrict__ wfo,
                                                   const ushort_t* __restrict__ wf1,
                                                   const ushort_t* __restrict__ wf2,
                                                   const float* __restrict__ bo,
                                                   const float* __restrict__ b1,
                                                   const float* __restrict__ b2,
                                                   const float* __restrict__ ga,
                                                   const float* __restrict__ gb) {
    __shared__ __align__(16) float regA[16 * XPITCH];  // fp32 x2 tile (padded)
    __shared__ __align__(16) char regB[8192];          // A-frag (attn-out, then xc)
    __shared__ __align__(16) char regC[8192];          // sidx/sws/vsumf, then h-frag
    const int tid = threadIdx.x, lane = tid & 63, w = tid >> 6;
    const int wid = (blockIdx.x & 7) * 64 + (blockIdx.x >> 3);   // XCD affinity
    const int R0 = wid * 16, bb = wid >> 5;
    int* sidx = (int*)regC;
    float* sws = (float*)(regC + 2048);
    float* vsumf = (float*)(regC + 4096);
    // ---- ph1: topk lists (16 rows x 32) + vsum reduce from global partials
    for (int i = tid; i < 512; i += 256) {
        int r = i >> 5;
        int nb = tidx[(size_t)(R0 + r) * NTOPK + (i & 31)];
        float wv = tw[(size_t)(R0 + r) * NTOPK + (i & 31)] * 0.17677669529663687f;
        sidx[i] = (msk[bb * NM + nb] == 0) ? (nb | (int)0x80000000) : nb;
        sws[i] = wv;
    }
    {
        float s = 0.f;
        #pragma unroll
        for (int s8 = 0; s8 < 8; ++s8) s += part[((size_t)(bb * 8 + s8)) * NHID + tid];
        vsumf[tid] = s;
    }
    __syncthreads();
    // ---- ph2: sparse attention; 4 rows/wave, 16 lanes/row
    {
        const int rr = lane >> 4;
        const int rl = (w << 2) + rr;            // local row 0..15
        const int row = R0 + rl;
        const int cbase = ((lane >> 1) & 7) * 32 + (lane & 1) * 16;
        const float* qp = q + (size_t)row * NHID + cbase;
        float qv[16];
        {
            f32x4 q0 = *(const f32x4*)(qp), q1 = *(const f32x4*)(qp + 4);
            f32x4 q2 = *(const f32x4*)(qp + 8), q3 = *(const f32x4*)(qp + 12);
            #pragma unroll
            for (int k = 0; k < 4; ++k) { qv[k]=q0[k]; qv[4+k]=q1[k]; qv[8+k]=q2[k]; qv[12+k]=q3[k]; }
        }
        float accv[16];
        #pragma unroll
        for (int k = 0; k < 16; ++k) accv[k] = 0.f;
        float den = 0.f;
        for (int j = 0; j < NTOPK; ++j) {
            int raw = sidx[rl * 32 + j];
            float swv = sws[rl * 32 + j];
            int nb = raw & 511;
            const ushort_t* kp = kvb + ((size_t)(bb * NM + nb)) * 512 + cbase;
            short8 kA = *(const short8*)(kp);
            short8 kB = *(const short8*)(kp + 8);
            short8 vA = *(const short8*)(kp + 256);
            short8 vB = *(const short8*)(kp + 264);
            float p = 0.f;
            #pragma unroll
            for (int t = 0; t < 8; ++t) p += qv[t] * b2f((ushort_t)kA[t]);
            #pragma unroll
            for (int t = 0; t < 8; ++t) p += qv[8 + t] * b2f((ushort_t)kB[t]);
            p += __shfl_xor(p, 1);
            float sarg = (raw < 0) ? -1e12f : p;
            float e = __expf(sarg * swv);
            float em1 = e - 1.0f;
            den += em1;
            #pragma unroll
            for (int t = 0; t < 8; ++t) accv[t] += em1 * b2f((ushort_t)vA[t]);
            #pragma unroll
            for (int t = 0; t < 8; ++t) accv[8 + t] += em1 * b2f((ushort_t)vB[t]);
        }
        float rden = 1.0f / (den + 512.0f);
        short8 p0, p1;
        #pragma unroll
        for (int t = 0; t < 8; ++t) {
            p0[t] = (short)f2b((accv[t] + vsumf[cbase + t]) * rden);
            p1[t] = (short)f2b((accv[8 + t] + vsumf[cbase + 8 + t]) * rden);
        }
        int c8 = cbase >> 3;
        *(short8*)(regB + FRAG_OFF(rl, c8)) = p0;
        *(short8*)(regB + FRAG_OFF(rl, c8 + 1)) = p1;
    }
    __syncthreads();
    // ---- ph3: Wo GEMM + mish + residual(x) -> regA
    {
        short8 a[8];
        #pragma unroll
        for (int ks = 0; ks < 8; ++ks) a[ks] = *(const short8*)(regB + FRAG_RD(ks, lane));
        #pragma unroll
        for (int g = 0; g < 2; ++g) {
            const int col0 = g * 128 + w * 32;
            f32x4 acc0 = {}, acc1 = {};
            const ushort_t* bp0 = wfo + ((size_t)((col0 >> 4) * 8) * 64 + lane) * 8;
            const ushort_t* bp1 = bp0 + 4096;
            #pragma unroll
            for (int ks = 0; ks < 8; ++ks) {
                short8 b0 = *(const short8*)(bp0 + ks * 512);
                short8 b1 = *(const short8*)(bp1 + ks * 512);
                acc0 = __builtin_amdgcn_mfma_f32_16x16x32_bf16(a[ks], b0, acc0, 0, 0, 0);
                acc1 = __builtin_amdgcn_mfma_f32_16x16x32_bf16(a[ks], b1, acc1, 0, 0, 0);
            }
            #pragma unroll
            for (int ni = 0; ni < 2; ++ni) {
                int col = col0 + ni * 16 + (lane & 15);
                float bv = bo[col];
                f32x4 A = ni ? acc1 : acc0;
                #pragma unroll
                for (int j = 0; j < 4; ++j) {
                    int row = (lane >> 4) * 4 + j;
                    float v = mish_f(A[j] + bv) + x[(size_t)(R0 + row) * NHID + col];
                    regA[row * XPITCH + col] = v;
                }
            }
        }
    }
    __syncthreads();
    // ---- ph4: LN2 on regA (in place) + frag -> regB
    {
        const int rr = lane >> 4, c16 = (lane & 15) << 4;
        const int rl = (w << 2) + rr;
        float* xr = regA + rl * XPITCH + c16;
        f32x4 v0 = *(const f32x4*)(xr);
        f32x4 v1 = *(const f32x4*)(xr + 4);
        f32x4 v2 = *(const f32x4*)(xr + 8);
        f32x4 v3 = *(const f32x4*)(xr + 12);
        float s = 0.f;
        #pragma unroll
        for (int k = 0; k < 4; ++k) s += v0[k] + v1[k] + v2[k] + v3[k];
        s += __shfl_xor(s, 1); s += __shfl_xor(s, 2); s += __shfl_xor(s, 4); s += __shfl_xor(s, 8);
        float mean = s * (1.0f / NHID);
        float vr = 0.f;
        #pragma unroll
        for (int k = 0; k < 4; ++k) {
            float d0 = v0[k]-mean, d1 = v1[k]-mean, d2 = v2[k]-mean, d3 = v3[k]-mean;
            vr += d0*d0 + d1*d1 + d2*d2 + d3*d3;
        }
        vr += __shfl_xor(vr, 1); vr += __shfl_xor(vr, 2); vr += __shfl_xor(vr, 4); vr += __shfl_xor(vr, 8);
        vr *= (1.0f / (NHID - 1));
        float rs = 1.0f / (sqrtf(vr) + 1e-6f);
        f32x4 g0 = *(const f32x4*)(ga + c16), g1 = *(const f32x4*)(ga + c16 + 4);
        f32x4 g2 = *(const f32x4*)(ga + c16 + 8), g3 = *(const f32x4*)(ga + c16 + 12);
        f32x4 h0 = *(const f32x4*)(gb + c16), h1 = *(const f32x4*)(gb + c16 + 4);
        f32x4 h2 = *(const f32x4*)(gb + c16 + 8), h3 = *(const f32x4*)(gb + c16 + 12);
        f32x4 o0, o1, o2, o3;
        #pragma unroll
        for (int k = 0; k < 4; ++k) {
            o0[k] = g0[k]*(v0[k]-mean)*rs + h0[k];
            o1[k] = g1[k]*(v1[k]-mean)*rs + h1[k];
            o2[k] = g2[k]*(v2[k]-mean)*rs + h2[k];
            o3[k] = g3[k]*(v3[k]-mean)*rs + h3[k];
        }
        *(f32x4*)(xr) = o0; *(f32x4*)(xr + 4) = o1;
        *(f32x4*)(xr + 8) = o2; *(f32x4*)(xr + 12) = o3;
        short8 p0, p1;
        #pragma unroll
        for (int k = 0; k < 4; ++k) {
            p0[k] = (short)f2b(o0[k]); p0[4+k] = (short)f2b(o1[k]);
            p1[k] = (short)f2b(o2[k]); p1[4+k] = (short)f2b(o3[k]);
        }
        int c8 = (lane & 15) * 2;
        *(short8*)(regB + FRAG_OFF(rl, c8)) = p0;
        *(short8*)(regB + FRAG_OFF(rl, c8 + 1)) = p1;
    }
    __syncthreads();
    // ---- ph5: FFN1 (mish) -> h-frag in regC (topk/vsum data dead)
    {
        short8 a[8];
        #pragma unroll
        for (int ks = 0; ks < 8; ++ks) a[ks] = *(const short8*)(regB + FRAG_RD(ks, lane));
        #pragma unroll
        for (int g = 0; g < 2; ++g) {
            const int col0 = g * 128 + w * 32;
            f32x4 acc0 = {}, acc1 = {};
            const ushort_t* bp0 = wf1 + ((size_t)((col0 >> 4) * 8) * 64 + lane) * 8;
            const ushort_t* bp1 = bp0 + 4096;
            #pragma unroll
            for (int ks = 0; ks < 8; ++ks) {
                short8 b0 = *(const short8*)(bp0 + ks * 512);
                short8 b1 = *(const short8*)(bp1 + ks * 512);
                acc0 = __builtin_amdgcn_mfma_f32_16x16x32_bf16(a[ks], b0, acc0, 0, 0, 0);
                acc1 = __builtin_amdgcn_mfma_f32_16x16x32_bf16(a[ks], b1, acc1, 0, 0, 0);
            }
            #pragma unroll
            for (int ni = 0; ni < 2; ++ni) {
                int col = col0 + ni * 16 + (lane & 15);
                float bv = b1[col];
                int c8 = col >> 3;
                f32x4 A = ni ? acc1 : acc0;
                #pragma unroll
                for (int j = 0; j < 4; ++j) {
                    int row = (lane >> 4) * 4 + j;
                    float v = mish_f(A[j] + bv);
                    *(ushort_t*)(regC + FRAG_OFF(row, c8) + (col & 7) * 2) = f2b(v);
                }
            }
        }
    }
    __syncthreads();
    // ---- ph6: FFN2 (mish) + residual(regA) -> global x
    {
        short8 a[8];
        #pragma unroll
        for (int ks = 0; ks < 8; ++ks) a[ks] = *(const short8*)(regC + FRAG_RD(ks, lane));
        #pragma unroll
        for (int g = 0; g < 2; ++g) {
            const int col0 = g * 128 + w * 32;
            f32x4 acc0 = {}, acc1 = {};
            const ushort_t* bp0 = wf2 + ((size_t)((col0 >> 4) * 8) * 64 + lane) * 8;
            const ushort_t* bp1 = bp0 + 4096;
            #pragma unroll
            for (int ks = 0; ks < 8; ++ks) {
                short8 b0 = *(const short8*)(bp0 + ks * 512);
                short8 b1 = *(const short8*)(bp1 + ks * 512);
                acc0 = __builtin_amdgcn_mfma_f32_16x16x32_bf16(a[ks], b0, acc0, 0, 0, 0);
                acc1 = __builtin_amdgcn_mfma_f32_16x16x32_bf16(a[ks], b1, acc1, 0, 0, 0);
            }
            #pragma unroll
            for (int ni = 0; ni < 2; ++ni) {
                int col = col0 + ni * 16 + (lane & 15);
                float bv = b2[col];
                f32x4 A = ni ? acc1 : acc0;
                #pragma unroll
                for (int j = 0; j < 4; ++j) {
                    int row = (lane >> 4) * 4 + j;
                    float v = mish_f(A[j] + bv) + regA[row * XPITCH + col];
                    x[(size_t)(R0 + row) * NHID + col] = v;
                }
            }
        }
    }
}

extern "C" void kernel_launch(void* const* d_in, const int* in_sizes, int n_in,
                              void* d_out, int out_size, void* d_ws, size_t ws_size,
                              hipStream_t stream) {
    (void)in_sizes; (void)n_in; (void)out_size; (void)ws_size;
    const float* node  = (const float*)d_in[0];
    const float* edge  = (const float*)d_in[1];
    const int*   msk   = (const int*)d_in[2];
    const float* attnW = (const float*)d_in[3];
    const float* attnB = (const float*)d_in[4];
    const float* ffnW  = (const float*)d_in[5];
    const float* ffnB  = (const float*)d_in[6];
    const float* lna   = (const float*)d_in[7];
    const float* lnb   = (const float*)d_in[8];

    float* x = (float*)d_out;                       // running activation [8192,256] fp32
    float* wsf = (float*)d_ws;
    // workspace: 5,537,792 floats = 21.1 MB
    float*    q    = wsf;                           // [8192,256] fp32
    ushort_t* kvb  = (ushort_t*)(wsf + 2097152);    // [8192,512] bf16
    ushort_t* wb   = (ushort_t*)(wsf + 4194304);    // 1,572,864 bf16 frag weights
    float*    tw   = wsf + 4980736;                 // [8192,32]
    int*      tidx = (int*)(wsf + 5242880);         // [8192,32]
    float*    part = wsf + 5505024;                 // [16,8,256]

    wconv_kernel<<<768, 256, 0, stream>>>(attnW, ffnW, wb);
    topk_kernel<<<2048, 256, 0, stream>>>(edge, tidx, tw);

    for (int l = 0; l < NLAYER; ++l) {
        k1_ln_qkv<<<dim3(512, 2), 256, 0, stream>>>(
            l == 0 ? node : x, x, q, kvb,
            wb + (size_t)(l * 64) * 4096, attnB + (size_t)l * 1024, lna, lnb);
        vpart_kernel<<<dim3(16, 8), 256, 0, stream>>>(kvb, part);
        k2_attn_ffn<<<512, 256, 0, stream>>>(
            x, q, kvb, tidx, tw, msk, part,
            wb + (size_t)(l * 64 + 48) * 4096,
            wb + (size_t)(256 + l * 32) * 4096,
            wb + (size_t)(256 + l * 32 + 16) * 4096,
            attnB + (size_t)l * 1024 + 768,
            ffnB + (size_t)l * 512,
            ffnB + (size_t)l * 512 + 256,
            lna, lnb);
    }
}

// Round 7
// 194.790 us; speedup vs baseline: 5.0457x; 1.2023x over previous
//
#include <hip/hip_runtime.h>
#include <cstddef>

#define NB 16
#define NM 512
#define NHID 256
#define NTOPK 32
#define NROWS (NB*NM)
#define NLAYER 4
#define XPITCH 260   // padded LDS row stride (floats); 260*4=1040B = 65*16 (16B-aligned, bank-shifted)

typedef unsigned short ushort_t;
typedef __attribute__((ext_vector_type(8))) short short8;
typedef __attribute__((ext_vector_type(4))) float f32x4;

// MFMA A-fragment LDS layout with bank-decorrelating XOR (verified rounds 5-6).
#define FRAG_OFF(row, c8) (((c8) >> 2) * 1024 + ((((c8) & 3) << 4) + (((row) & 15) ^ ((c8) >> 2))) * 16)
#define FRAG_RD(ks, lane) ((ks) * 1024 + ((((lane) >> 4) << 4) + (((lane) & 15) ^ (ks))) * 16)

#define MFMA16(a, b, c) __builtin_amdgcn_mfma_f32_16x16x32_bf16((a), (b), (c), 0, 0, 0)

// mish(v) = v*tanh(softplus(v)) = v*(t^2+2t)/(t^2+2t+2), t=e^v
__device__ __forceinline__ float mish_f(float v) {
    if (v > 20.0f) return v;
    float t = __expf(v);
    float u = t * (t + 2.0f);
    return v * (u / (u + 2.0f));
}
__device__ __forceinline__ ushort_t f2b(float f) {   // fp32 -> bf16 RNE
    unsigned u = __float_as_uint(f);
    return (ushort_t)((u + 0x7FFFu + ((u >> 16) & 1u)) >> 16);
}
__device__ __forceinline__ float b2f(ushort_t h) {
    return __uint_as_float(((unsigned)h) << 16);
}

// ---------------- prep: wconv (768 blocks) + topk (2048 blocks) --------------
__global__ __launch_bounds__(256) void prep_kernel(const float* __restrict__ edge,
                                                   int* __restrict__ tidx,
                                                   float* __restrict__ tw,
                                                   const float* __restrict__ attnW,
                                                   const float* __restrict__ ffnW,
                                                   ushort_t* __restrict__ wb) {
    if (blockIdx.x < 768) {
        // weight conversion into MFMA-fragment layout
        int t = blockIdx.x * 256 + threadIdx.x;      // 196608 threads
        int frag = t >> 9, r = t & 511;
        int ks = r >> 6, l = r & 63;
        const float* src;
        if (frag < 256) src = attnW + ((size_t)(frag >> 6) * 1024 + (frag & 63) * 16 + (l & 15)) * 256;
        else { int fi = frag - 256; src = ffnW + ((size_t)(fi >> 5) * 512 + (fi & 31) * 16 + (l & 15)) * 256; }
        src += ks * 32 + (l >> 4) * 8;
        short8 o;
        #pragma unroll
        for (int j = 0; j < 8; ++j) o[j] = (short)f2b(src[j]);
        *(short8*)(wb + (size_t)t * 8) = o;
        return;
    }
    // top-k: ballot bisection, one wave per row (tw pre-scaled by 1/sqrt(32))
    const int lane = threadIdx.x & 63, w = threadIdx.x >> 6;
    const int row = (blockIdx.x - 768) * 4 + w;
    const float* er = edge + (size_t)row * NM;
    float v[8]; unsigned u[8];
    #pragma unroll
    for (int s = 0; s < 8; ++s) { v[s] = er[s * 64 + lane]; u[s] = __float_as_uint(v[s]); }
    unsigned T = 0;
    for (int bit = 31; bit >= 0; --bit) {
        unsigned Tc = T | (1u << bit);
        int c = 0;
        #pragma unroll
        for (int s = 0; s < 8; ++s) c += (int)__popcll(__ballot(u[s] >= Tc));
        if (c >= NTOPK) T = Tc;
    }
    int cgt = 0;
    #pragma unroll
    for (int s = 0; s < 8; ++s) cgt += (int)__popcll(__ballot(u[s] > T));
    const int extra = NTOPK - cgt;
    float psum = 0.f;
    #pragma unroll
    for (int s = 0; s < 8; ++s) psum += (u[s] > T) ? v[s] : 0.f;
    psum += __shfl_xor(psum, 1); psum += __shfl_xor(psum, 2); psum += __shfl_xor(psum, 4);
    psum += __shfl_xor(psum, 8); psum += __shfl_xor(psum, 16); psum += __shfl_xor(psum, 32);
    const float ssum = psum + (float)extra * __uint_as_float(T);
    const float rden = 0.17677669529663687f / (ssum + 1e-5f);
    const unsigned long long lmask = (1ull << lane) - 1ull;
    int base = 0, eqbase = 0;
    #pragma unroll
    for (int s = 0; s < 8; ++s) {
        bool gt = (u[s] > T), eq = (u[s] == T);
        unsigned long long meq = __ballot(eq);
        int eqrank = eqbase + (int)__popcll(meq & lmask);
        bool sel = gt || (eq && eqrank < extra);
        unsigned long long msel = __ballot(sel);
        if (sel) {
            int pos = base + (int)__popcll(msel & lmask);
            tidx[row * NTOPK + pos] = s * 64 + lane;
            tw[row * NTOPK + pos] = v[s] * rden;
        }
        base += (int)__popcll(msel);
        eqbase += (int)__popcll(meq);
    }
}

// ---------------- K1: LN1 + QKV GEMM (layer 0) + V-partials ------------------
__global__ __launch_bounds__(256) void k1_ln_qkv(const float* __restrict__ xin,
                                                 float* __restrict__ x,
                                                 float* __restrict__ q,
                                                 ushort_t* __restrict__ kvb,
                                                 float* __restrict__ part,
                                                 const ushort_t* __restrict__ wf,
                                                 const float* __restrict__ bias,
                                                 const float* __restrict__ ga,
                                                 const float* __restrict__ gb) {
    __shared__ __align__(16) char af[8192];      // A-fragments, 16 rows x 256 cols bf16
    const int tid = threadIdx.x, lane = tid & 63, w = tid >> 6;
    const int bx = blockIdx.x;
    const int wid = (bx & 7) * 64 + (bx >> 3);   // XCD affinity
    const int bm = wid * 16, bb = wid >> 5, blk = wid & 31;
    const int zb = blockIdx.y;                   // column half
    {
        const int rr = lane >> 4, c16 = (lane & 15) << 4;
        const int ri = (w << 2) + rr;
        const float* xr = xin + (size_t)(bm + ri) * NHID + c16;
        f32x4 v0 = *(const f32x4*)(xr);
        f32x4 v1 = *(const f32x4*)(xr + 4);
        f32x4 v2 = *(const f32x4*)(xr + 8);
        f32x4 v3 = *(const f32x4*)(xr + 12);
        float s = 0.f;
        #pragma unroll
        for (int k = 0; k < 4; ++k) s += v0[k] + v1[k] + v2[k] + v3[k];
        s += __shfl_xor(s, 1); s += __shfl_xor(s, 2); s += __shfl_xor(s, 4); s += __shfl_xor(s, 8);
        float mean = s * (1.0f / NHID);
        float vr = 0.f;
        #pragma unroll
        for (int k = 0; k < 4; ++k) {
            float d0 = v0[k]-mean, d1 = v1[k]-mean, d2 = v2[k]-mean, d3 = v3[k]-mean;
            vr += d0*d0 + d1*d1 + d2*d2 + d3*d3;
        }
        vr += __shfl_xor(vr, 1); vr += __shfl_xor(vr, 2); vr += __shfl_xor(vr, 4); vr += __shfl_xor(vr, 8);
        vr *= (1.0f / (NHID - 1));
        float rs = 1.0f / (sqrtf(vr) + 1e-6f);
        f32x4 g0 = *(const f32x4*)(ga + c16), g1 = *(const f32x4*)(ga + c16 + 4);
        f32x4 g2 = *(const f32x4*)(ga + c16 + 8), g3 = *(const f32x4*)(ga + c16 + 12);
        f32x4 h0 = *(const f32x4*)(gb + c16), h1 = *(const f32x4*)(gb + c16 + 4);
        f32x4 h2 = *(const f32x4*)(gb + c16 + 8), h3 = *(const f32x4*)(gb + c16 + 12);
        f32x4 o0, o1, o2, o3;
        #pragma unroll
        for (int k = 0; k < 4; ++k) {
            o0[k] = g0[k]*(v0[k]-mean)*rs + h0[k];
            o1[k] = g1[k]*(v1[k]-mean)*rs + h1[k];
            o2[k] = g2[k]*(v2[k]-mean)*rs + h2[k];
            o3[k] = g3[k]*(v3[k]-mean)*rs + h3[k];
        }
        if (zb == 0) {
            float* xw = x + (size_t)(bm + ri) * NHID + c16;
            *(f32x4*)(xw) = o0; *(f32x4*)(xw + 4) = o1;
            *(f32x4*)(xw + 8) = o2; *(f32x4*)(xw + 12) = o3;
        }
        short8 p0, p1;
        #pragma unroll
        for (int k = 0; k < 4; ++k) {
            p0[k] = (short)f2b(o0[k]); p0[4+k] = (short)f2b(o1[k]);
            p1[k] = (short)f2b(o2[k]); p1[4+k] = (short)f2b(o3[k]);
        }
        int c8 = (lane & 15) * 2;
        *(short8*)(af + FRAG_OFF(ri, c8)) = p0;
        *(short8*)(af + FRAG_OFF(ri, c8 + 1)) = p1;
    }
    __syncthreads();
    short8 a[8];
    #pragma unroll
    for (int ks = 0; ks < 8; ++ks) a[ks] = *(const short8*)(af + FRAG_RD(ks, lane));
    #pragma unroll
    for (int gi = 0; gi < 3; ++gi) {
        const int col0 = (zb * 3 + gi) * 128 + w * 32;
        f32x4 acc0 = {}, acc1 = {};
        const ushort_t* bp0 = wf + ((size_t)((col0 >> 4) * 8) * 64 + lane) * 8;
        const ushort_t* bp1 = bp0 + 4096;
        #pragma unroll
        for (int ks = 0; ks < 8; ++ks) {
            short8 b0 = *(const short8*)(bp0 + ks * 512);
            short8 b1 = *(const short8*)(bp1 + ks * 512);
            acc0 = MFMA16(a[ks], b0, acc0);
            acc1 = MFMA16(a[ks], b1, acc1);
        }
        const int rbase = bm + (lane >> 4) * 4;
        #pragma unroll
        for (int ni = 0; ni < 2; ++ni) {
            int col = col0 + ni * 16 + (lane & 15);
            float bv = bias[col];
            f32x4 A = ni ? acc1 : acc0;
            #pragma unroll
            for (int j = 0; j < 4; ++j) {
                int row = rbase + j;
                float vv = A[j] + bv;
                if (col < 256) q[(size_t)row * 256 + col] = vv;
                else kvb[(size_t)row * 512 + (col - 256)] = f2b(vv);
            }
            if (zb == 1 && gi >= 1) {      // V columns: per-block column partial sum
                float s2 = A[0] + A[1] + A[2] + A[3] + 4.0f * bv;
                s2 += __shfl_xor(s2, 16); s2 += __shfl_xor(s2, 32);
                if (lane < 16)
                    part[((size_t)bb * 32 + blk) * 256 + (col0 + ni * 16 + lane - 512)] = s2;
            }
        }
    }
}

// ---------------- KB: attn + Wo + LN2 + FFN + [LN1' + QKV'] (16 rows) --------
template<int LAST>
__global__ __launch_bounds__(512) void kb_layer(float* __restrict__ x,
                                                float* __restrict__ q,
                                                const ushort_t* __restrict__ kvb_cur,
                                                ushort_t* __restrict__ kvb_nxt,
                                                const float* __restrict__ part_cur,
                                                float* __restrict__ part_nxt,
                                                const int* __restrict__ tidx,
                                                const float* __restrict__ tw,
                                                const int* __restrict__ msk,
                                                const ushort_t* __restrict__ wfo,
                                                const ushort_t* __restrict__ wf1,
                                                const ushort_t* __restrict__ wf2,
                                                const ushort_t* __restrict__ wqn,
                                                const float* __restrict__ bo,
                                                const float* __restrict__ b1,
                                                const float* __restrict__ b2,
                                                const float* __restrict__ bqn,
                                                const float* __restrict__ ga,
                                                const float* __restrict__ gb) {
    __shared__ __align__(16) float regA[16 * XPITCH];  // fp32 x2 tile
    __shared__ __align__(16) char regB[8192];          // bf16 A-frags
    __shared__ __align__(16) char regC[8192];          // sidx/sws/vsumf, then h-frag
    const int tid = threadIdx.x, lane = tid & 63, w = tid >> 6;
    const int wid = (blockIdx.x & 7) * 64 + (blockIdx.x >> 3);   // XCD affinity
    const int R0 = wid * 16, bb = wid >> 5, blk = wid & 31;
    int* sidx = (int*)regC;
    float* sws = (float*)(regC + 2048);
    float* vsumf = (float*)(regC + 4096);
    // ---- ph1: stage topk lists (512 entries), vsum reduce, load q
    {
        int nb = tidx[(size_t)R0 * NTOPK + tid];
        float wv = tw[(size_t)R0 * NTOPK + tid];
        sidx[tid] = (msk[bb * NM + nb] == 0) ? (nb | (int)0x80000000) : nb;
        sws[tid] = wv;
        if (tid < 256) {
            float s = 0.f;
            #pragma unroll
            for (int p = 0; p < 32; ++p) s += part_cur[((size_t)bb * 32 + p) * 256 + tid];
            vsumf[tid] = s;
        }
    }
    const int arow = tid >> 5;            // local row 0..15 (32 lanes each)
    const int cbase = (tid & 31) * 8;     // 8 cols per lane
    float qv[8];
    {
        const float* qp = q + (size_t)(R0 + arow) * 256 + cbase;
        f32x4 q0 = *(const f32x4*)qp, q1 = *(const f32x4*)(qp + 4);
        #pragma unroll
        for (int k = 0; k < 4; ++k) { qv[k] = q0[k]; qv[4 + k] = q1[k]; }
    }
    __syncthreads();
    // ---- ph2: sparse attention
    {
        float accv[8] = {};
        float den = 0.f;
        for (int j = 0; j < NTOPK; ++j) {
            int raw = sidx[arow * 32 + j];
            float swv = sws[arow * 32 + j];
            int nb = raw & 511;
            const ushort_t* kp = kvb_cur + ((size_t)(bb * NM + nb)) * 512 + cbase;
            short8 kA = *(const short8*)(kp);
            short8 vA = *(const short8*)(kp + 256);
            float p = 0.f;
            #pragma unroll
            for (int t = 0; t < 8; ++t) p += qv[t] * b2f((ushort_t)kA[t]);
            p += __shfl_xor(p, 1); p += __shfl_xor(p, 2); p += __shfl_xor(p, 4);
            p += __shfl_xor(p, 8); p += __shfl_xor(p, 16);
            float sarg = (raw < 0) ? -1e12f : p;
            float e = __expf(sarg * swv);
            float em1 = e - 1.0f;
            den += em1;
            #pragma unroll
            for (int t = 0; t < 8; ++t) accv[t] += em1 * b2f((ushort_t)vA[t]);
        }
        float rden = 1.0f / (den + 512.0f);
        short8 p0;
        #pragma unroll
        for (int t = 0; t < 8; ++t) p0[t] = (short)f2b((accv[t] + vsumf[cbase + t]) * rden);
        *(short8*)(regB + FRAG_OFF(arow, (tid & 31))) = p0;
    }
    __syncthreads();
    // ---- ph3: Wo GEMM + mish + residual(x = LN1-out) -> regA
    {
        short8 a[8];
        #pragma unroll
        for (int ks = 0; ks < 8; ++ks) a[ks] = *(const short8*)(regB + FRAG_RD(ks, lane));
        const int col0 = w * 32;
        f32x4 acc0 = {}, acc1 = {};
        const ushort_t* bp0 = wfo + ((size_t)((col0 >> 4) * 8) * 64 + lane) * 8;
        const ushort_t* bp1 = bp0 + 4096;
        #pragma unroll
        for (int ks = 0; ks < 8; ++ks) {
            short8 b0 = *(const short8*)(bp0 + ks * 512);
            short8 b1 = *(const short8*)(bp1 + ks * 512);
            acc0 = MFMA16(a[ks], b0, acc0);
            acc1 = MFMA16(a[ks], b1, acc1);
        }
        #pragma unroll
        for (int ni = 0; ni < 2; ++ni) {
            int col = col0 + ni * 16 + (lane & 15);
            float bv = bo[col];
            f32x4 A = ni ? acc1 : acc0;
            #pragma unroll
            for (int j = 0; j < 4; ++j) {
                int row = (lane >> 4) * 4 + j;
                regA[row * XPITCH + col] = mish_f(A[j] + bv) + x[(size_t)(R0 + row) * NHID + col];
            }
        }
    }
    __syncthreads();
    // ---- ph4: LN2 on regA (keep normed in regA for FFN2 residual) + frag->regB
    {
        const int lrow = (w << 1) | (lane >> 5);
        const int c0 = (lane & 31) * 8;
        float* xr = regA + lrow * XPITCH + c0;
        f32x4 v0 = *(const f32x4*)xr, v1 = *(const f32x4*)(xr + 4);
        float s = v0[0]+v0[1]+v0[2]+v0[3]+v1[0]+v1[1]+v1[2]+v1[3];
        s += __shfl_xor(s,1); s += __shfl_xor(s,2); s += __shfl_xor(s,4);
        s += __shfl_xor(s,8); s += __shfl_xor(s,16);
        float mean = s * (1.0f / NHID);
        float vr = 0.f;
        #pragma unroll
        for (int k = 0; k < 4; ++k) {
            float d0 = v0[k]-mean, d1 = v1[k]-mean;
            vr += d0*d0 + d1*d1;
        }
        vr += __shfl_xor(vr,1); vr += __shfl_xor(vr,2); vr += __shfl_xor(vr,4);
        vr += __shfl_xor(vr,8); vr += __shfl_xor(vr,16);
        vr *= (1.0f / (NHID - 1));
        float rs = 1.0f / (sqrtf(vr) + 1e-6f);
        f32x4 g0 = *(const f32x4*)(ga + c0), g1 = *(const f32x4*)(ga + c0 + 4);
        f32x4 h0 = *(const f32x4*)(gb + c0), h1 = *(const f32x4*)(gb + c0 + 4);
        f32x4 o0, o1;
        #pragma unroll
        for (int k = 0; k < 4; ++k) {
            o0[k] = g0[k]*(v0[k]-mean)*rs + h0[k];
            o1[k] = g1[k]*(v1[k]-mean)*rs + h1[k];
        }
        *(f32x4*)xr = o0; *(f32x4*)(xr + 4) = o1;
        short8 p;
        #pragma unroll
        for (int k = 0; k < 4; ++k) { p[k] = (short)f2b(o0[k]); p[4+k] = (short)f2b(o1[k]); }
        *(short8*)(regB + FRAG_OFF(lrow, (lane & 31))) = p;
    }
    __syncthreads();
    // ---- ph5: FFN1 (mish) -> h-frag in regC
    {
        short8 a[8];
        #pragma unroll
        for (int ks = 0; ks < 8; ++ks) a[ks] = *(const short8*)(regB + FRAG_RD(ks, lane));
        const int col0 = w * 32;
        f32x4 acc0 = {}, acc1 = {};
        const ushort_t* bp0 = wf1 + ((size_t)((col0 >> 4) * 8) * 64 + lane) * 8;
        const ushort_t* bp1 = bp0 + 4096;
        #pragma unroll
        for (int ks = 0; ks < 8; ++ks) {
            short8 b0 = *(const short8*)(bp0 + ks * 512);
            short8 b1 = *(const short8*)(bp1 + ks * 512);
            acc0 = MFMA16(a[ks], b0, acc0);
            acc1 = MFMA16(a[ks], b1, acc1);
        }
        #pragma unroll
        for (int ni = 0; ni < 2; ++ni) {
            int col = col0 + ni * 16 + (lane & 15);
            float bv = b1[col];
            int c8 = col >> 3;
            f32x4 A = ni ? acc1 : acc0;
            #pragma unroll
            for (int j = 0; j < 4; ++j) {
                int row = (lane >> 4) * 4 + j;
                *(ushort_t*)(regC + FRAG_OFF(row, c8) + (col & 7) * 2) = f2b(mish_f(A[j] + bv));
            }
        }
    }
    __syncthreads();
    // ---- ph6: FFN2 (mish) + residual(regA = LN2-out)
    {
        short8 a[8];
        #pragma unroll
        for (int ks = 0; ks < 8; ++ks) a[ks] = *(const short8*)(regC + FRAG_RD(ks, lane));
        const int col0 = w * 32;
        f32x4 acc0 = {}, acc1 = {};
        const ushort_t* bp0 = wf2 + ((size_t)((col0 >> 4) * 8) * 64 + lane) * 8;
        const ushort_t* bp1 = bp0 + 4096;
        #pragma unroll
        for (int ks = 0; ks < 8; ++ks) {
            short8 b0 = *(const short8*)(bp0 + ks * 512);
            short8 b1 = *(const short8*)(bp1 + ks * 512);
            acc0 = MFMA16(a[ks], b0, acc0);
            acc1 = MFMA16(a[ks], b1, acc1);
        }
        #pragma unroll
        for (int ni = 0; ni < 2; ++ni) {
            int col = col0 + ni * 16 + (lane & 15);
            float bv = b2[col];
            f32x4 A = ni ? acc1 : acc0;
            #pragma unroll
            for (int j = 0; j < 4; ++j) {
                int row = (lane >> 4) * 4 + j;
                float v = mish_f(A[j] + bv) + regA[row * XPITCH + col];
                if (LAST) x[(size_t)(R0 + row) * NHID + col] = v;   // final output
                else regA[row * XPITCH + col] = v;                   // same-thread RMW
            }
        }
    }
    if (LAST) return;
    __syncthreads();
    // ---- ph7: LN1 of next layer on regA -> global x (residual base) + frag->regB
    {
        const int lrow = (w << 1) | (lane >> 5);
        const int c0 = (lane & 31) * 8;
        float* xr = regA + lrow * XPITCH + c0;
        f32x4 v0 = *(const f32x4*)xr, v1 = *(const f32x4*)(xr + 4);
        float s = v0[0]+v0[1]+v0[2]+v0[3]+v1[0]+v1[1]+v1[2]+v1[3];
        s += __shfl_xor(s,1); s += __shfl_xor(s,2); s += __shfl_xor(s,4);
        s += __shfl_xor(s,8); s += __shfl_xor(s,16);
        float mean = s * (1.0f / NHID);
        float vr = 0.f;
        #pragma unroll
        for (int k = 0; k < 4; ++k) {
            float d0 = v0[k]-mean, d1 = v1[k]-mean;
            vr += d0*d0 + d1*d1;
        }
        vr += __shfl_xor(vr,1); vr += __shfl_xor(vr,2); vr += __shfl_xor(vr,4);
        vr += __shfl_xor(vr,8); vr += __shfl_xor(vr,16);
        vr *= (1.0f / (NHID - 1));
        float rs = 1.0f / (sqrtf(vr) + 1e-6f);
        f32x4 g0 = *(const f32x4*)(ga + c0), g1 = *(const f32x4*)(ga + c0 + 4);
        f32x4 h0 = *(const f32x4*)(gb + c0), h1 = *(const f32x4*)(gb + c0 + 4);
        f32x4 o0, o1;
        #pragma unroll
        for (int k = 0; k < 4; ++k) {
            o0[k] = g0[k]*(v0[k]-mean)*rs + h0[k];
            o1[k] = g1[k]*(v1[k]-mean)*rs + h1[k];
        }
        float* xg = x + (size_t)(R0 + lrow) * NHID + c0;
        *(f32x4*)xg = o0; *(f32x4*)(xg + 4) = o1;
        short8 p;
        #pragma unroll
        for (int k = 0; k < 4; ++k) { p[k] = (short)f2b(o0[k]); p[4+k] = (short)f2b(o1[k]); }
        *(short8*)(regB + FRAG_OFF(lrow, (lane & 31))) = p;
    }
    __syncthreads();
    // ---- ph8: QKV GEMM of next layer (+ V-partials into part_nxt)
    {
        short8 a[8];
        #pragma unroll
        for (int ks = 0; ks < 8; ++ks) a[ks] = *(const short8*)(regB + FRAG_RD(ks, lane));
        #pragma unroll
        for (int gg = 0; gg < 3; ++gg) {
            const int col0 = w * 96 + gg * 32;
            f32x4 acc0 = {}, acc1 = {};
            const ushort_t* bp0 = wqn + ((size_t)((col0 >> 4) * 8) * 64 + lane) * 8;
            const ushort_t* bp1 = bp0 + 4096;
            #pragma unroll
            for (int ks = 0; ks < 8; ++ks) {
                short8 b0 = *(const short8*)(bp0 + ks * 512);
                short8 b1 = *(const short8*)(bp1 + ks * 512);
                acc0 = MFMA16(a[ks], b0, acc0);
                acc1 = MFMA16(a[ks], b1, acc1);
            }
            #pragma unroll
            for (int ni = 0; ni < 2; ++ni) {
                int col = col0 + ni * 16 + (lane & 15);
                float bv = bqn[col];
                f32x4 A = ni ? acc1 : acc0;
                #pragma unroll
                for (int j = 0; j < 4; ++j) {
                    int row = (lane >> 4) * 4 + j;
                    float vv = A[j] + bv;
                    if (col < 256) q[(size_t)(R0 + row) * 256 + col] = vv;
                    else kvb_nxt[(size_t)(R0 + row) * 512 + (col - 256)] = f2b(vv);
                }
                if (col0 >= 512) {
                    float s2 = A[0] + A[1] + A[2] + A[3] + 4.0f * bv;
                    s2 += __shfl_xor(s2, 16); s2 += __shfl_xor(s2, 32);
                    if (lane < 16)
                        part_nxt[((size_t)bb * 32 + blk) * 256 + (col0 + ni * 16 + lane - 512)] = s2;
                }
            }
        }
    }
}

extern "C" void kernel_launch(void* const* d_in, const int* in_sizes, int n_in,
                              void* d_out, int out_size, void* d_ws, size_t ws_size,
                              hipStream_t stream) {
    (void)in_sizes; (void)n_in; (void)out_size; (void)ws_size;
    const float* node  = (const float*)d_in[0];
    const float* edge  = (const float*)d_in[1];
    const int*   msk   = (const int*)d_in[2];
    const float* attnW = (const float*)d_in[3];
    const float* attnB = (const float*)d_in[4];
    const float* ffnW  = (const float*)d_in[5];
    const float* ffnB  = (const float*)d_in[6];
    const float* lna   = (const float*)d_in[7];
    const float* lnb   = (const float*)d_in[8];

    float* x = (float*)d_out;                       // running activation [8192,256] fp32
    float* wsf = (float*)d_ws;
    // workspace: 7,864,320 floats = 30 MiB
    float*    q     = wsf;                          // [8192,256] fp32
    ushort_t* kvbA  = (ushort_t*)(wsf + 2097152);   // [8192,512] bf16
    ushort_t* kvbB  = (ushort_t*)(wsf + 4194304);   // [8192,512] bf16
    ushort_t* wb    = (ushort_t*)(wsf + 6291456);   // 1,572,864 bf16 frag weights
    float*    tw    = wsf + 7077888;                // [8192,32]
    int*      tidx  = (int*)(wsf + 7340032);        // [8192,32]
    float*    partA = wsf + 7602176;                // [16,32,256]
    float*    partB = wsf + 7733248;                // [16,32,256]

    prep_kernel<<<2816, 256, 0, stream>>>(edge, tidx, tw, attnW, ffnW, wb);
    k1_ln_qkv<<<dim3(512, 2), 256, 0, stream>>>(node, x, q, kvbA, partA,
                                                wb, attnB, lna, lnb);
    for (int l = 0; l < NLAYER; ++l) {
        ushort_t* kv_c = (l & 1) ? kvbB : kvbA;
        ushort_t* kv_n = (l & 1) ? kvbA : kvbB;
        float* pt_c = (l & 1) ? partB : partA;
        float* pt_n = (l & 1) ? partA : partB;
        const ushort_t* wfo = wb + (size_t)(l * 64 + 48) * 4096;
        const ushort_t* wf1 = wb + (size_t)(256 + l * 32) * 4096;
        const ushort_t* wf2 = wb + (size_t)(256 + l * 32 + 16) * 4096;
        const ushort_t* wqn = wb + (size_t)(((l + 1) & 3) * 64) * 4096;
        const float* bo  = attnB + (size_t)l * 1024 + 768;
        const float* b1  = ffnB + (size_t)l * 512;
        const float* b2  = b1 + 256;
        const float* bqn = attnB + (size_t)((l + 1) & 3) * 1024;
        if (l < NLAYER - 1)
            kb_layer<0><<<512, 512, 0, stream>>>(x, q, kv_c, kv_n, pt_c, pt_n,
                tidx, tw, msk, wfo, wf1, wf2, wqn, bo, b1, b2, bqn, lna, lnb);
        else
            kb_layer<1><<<512, 512, 0, stream>>>(x, q, kv_c, kv_n, pt_c, pt_n,
                tidx, tw, msk, wfo, wf1, wf2, wqn, bo, b1, b2, bqn, lna, lnb);
    }
}